// Round 7
// baseline (310.089 us; speedup 1.0000x reference)
//
#include <hip/hip_runtime.h>

typedef __attribute__((ext_vector_type(8))) short bf16x8;
typedef __attribute__((ext_vector_type(4))) float f32x4;
typedef unsigned short u16;
typedef unsigned int u32;

#define MFMA16(A, B, C) __builtin_amdgcn_mfma_f32_16x16x32_bf16((A), (B), (C), 0, 0, 0)

#if __has_builtin(__builtin_amdgcn_exp2f)
#define EXP2(x) __builtin_amdgcn_exp2f(x)
#else
#define EXP2(x) exp2f(x)
#endif

// REP: instrumentation — each GEMM dispatch internally repeats its full
// (idempotent) body 3x so its dispatch duration = 3x true duration. This
// surfaces the GEMMs in rocprof's top-5 (threshold = flash's 81 us) with
// their counters. Remove next round.
#define REP 3

typedef __attribute__((address_space(3))) unsigned int lds_u32;
typedef const __attribute__((address_space(1))) unsigned int glb_u32;

__device__ __forceinline__ u16 f2bf(float f) {
  union { float f; unsigned u; } x; x.f = f;
  unsigned r = (x.u + 0x7fffu + ((x.u >> 16) & 1u)) >> 16;
  return (u16)r;
}
__device__ __forceinline__ float bf2f(u16 h) {
  union { float f; unsigned u; } x; x.u = ((unsigned)h) << 16;
  return x.f;
}

// stage a 64x64 bf16 tile (ld=64) into contiguous LDS via global_load_lds,
// XOR-swizzled: LDS slot (row, c) holds global chunk c^(row&7).
__device__ __forceinline__ void stage_sw64(const u16* src, u16* lds, int tid) {
#pragma unroll
  for (int i = 0; i < 2; i++) {
    int vv = tid + i * 256;
    int row = vv >> 3, c = vv & 7;
    const u16* gp = src + (size_t)row * 64 + (size_t)(c ^ (row & 7)) * 8;
    __builtin_amdgcn_global_load_lds((glb_u32*)gp,
        (lds_u32*)(lds + (size_t)(i * 256 + (tid & 192)) * 8), 16, 0, 0);
  }
}

// stage ROWS x 64 bf16 tile from a row-major [*][512] matrix (ld=512) into
// contiguous LDS, same XOR swizzle.
template <int ROWS>
__device__ __forceinline__ void stage_ld512(const u16* src, u16* lds, int tid) {
#pragma unroll
  for (int i = 0; i < ROWS / 32; i++) {
    int vv = tid + i * 256;
    int row = vv >> 3, c = vv & 7;
    const u16* gp = src + (size_t)row * 512 + (size_t)(c ^ (row & 7)) * 8;
    __builtin_amdgcn_global_load_lds((glb_u32*)gp,
        (lds_u32*)(lds + (size_t)(i * 256 + (tid & 192)) * 8), 16, 0, 0);
  }
}

// ---------------- prep kernel (transposes only; cast folded into qkv) ----
// blocks [0,192): W_attn [512][1536] -> wta [1536][512] bf16
// blocks [192,256): W_out [512][512] -> whi/wlo transposed hi/lo
__global__ __launch_bounds__(256) void prep_kernel(const float* __restrict__ Wa,
                                                   u16* __restrict__ wta,
                                                   const float* __restrict__ Wo,
                                                   u16* __restrict__ whi,
                                                   u16* __restrict__ wlo) {
  __shared__ u16 Th[64][72];
  __shared__ u16 Tl[64][72];
  const int bid = blockIdx.x;
  const int tid = threadIdx.x;

  if (bid < 192) {
    const int t = bid;
    const int n0 = (t % 24) * 64;
    const int k0 = (t / 24) * 64;
    const int r = tid >> 4, c4 = (tid & 15) * 4;
#pragma unroll
    for (int i = 0; i < 4; i++) {
      int row = r + i * 16;
      float4 v = *(const float4*)&Wa[(size_t)(k0 + row) * 1536 + n0 + c4];
      Th[c4 + 0][row] = f2bf(v.x);
      Th[c4 + 1][row] = f2bf(v.y);
      Th[c4 + 2][row] = f2bf(v.z);
      Th[c4 + 3][row] = f2bf(v.w);
    }
    __syncthreads();
    const int row = tid >> 2, c16 = (tid & 3) * 16;
    *(uint4*)&wta[(size_t)(n0 + row) * 512 + k0 + c16]     = *(uint4*)&Th[row][c16];
    *(uint4*)&wta[(size_t)(n0 + row) * 512 + k0 + c16 + 8] = *(uint4*)&Th[row][c16 + 8];
    return;
  }

  {
    const int t = bid - 192;
    const int n0 = (t & 7) * 64;
    const int k0 = (t >> 3) * 64;
    const int r = tid >> 4, c4 = (tid & 15) * 4;
#pragma unroll
    for (int i = 0; i < 4; i++) {
      int row = r + i * 16;
      float4 v = *(const float4*)&Wo[(size_t)(k0 + row) * 512 + n0 + c4];
      float vv[4] = {v.x, v.y, v.z, v.w};
#pragma unroll
      for (int jj = 0; jj < 4; jj++) {
        u16 hi = f2bf(vv[jj]);
        Th[c4 + jj][row] = hi;
        Tl[c4 + jj][row] = f2bf(vv[jj] - bf2f(hi));
      }
    }
    __syncthreads();
    const int row = tid >> 2, c16 = (tid & 3) * 16;
    *(uint4*)&whi[(size_t)(n0 + row) * 512 + k0 + c16]     = *(uint4*)&Th[row][c16];
    *(uint4*)&whi[(size_t)(n0 + row) * 512 + k0 + c16 + 8] = *(uint4*)&Th[row][c16 + 8];
    *(uint4*)&wlo[(size_t)(n0 + row) * 512 + k0 + c16]     = *(uint4*)&Tl[row][c16];
    *(uint4*)&wlo[(size_t)(n0 + row) * 512 + k0 + c16 + 8] = *(uint4*)&Tl[row][c16 + 8];
  }
}

// ---------------- QKV GEMM (128x128 tile, cast folded, REP'd) ------------
// A is reg-staged DIRECTLY from x (f32), cast inline with the same f2bf as
// the old cast pass (identical numerics), ds_written XOR-swizzled. B via
// global_load_lds dbuf. LDS 48 KB -> 3 blocks/CU, 768 blocks = 1 round.
// Per K-step: prefetch(A-regs + B gload) issued BEFORE compute so the
// barrier drain lands after ~300cy of MFMA cover.
__global__ __launch_bounds__(256, 3) void gemm_qkv(const float* __restrict__ x,
                                                   const u16* __restrict__ wta,
                                                   const float* __restrict__ b_attn,
                                                   u16* __restrict__ q,
                                                   u16* __restrict__ kk,
                                                   u16* __restrict__ v) {
  __shared__ u16 A_lds[128 * 64];
  __shared__ u16 B_lds[2][128 * 64];
  const int bid = blockIdx.x;
  const int xcd = bid & 7, rr = bid >> 3;       // rr in [0,96)
  const int m0 = (xcd * 8 + (rr & 7)) * 128;    // 64 m-tiles
  const int n0 = (rr >> 3) * 128;               // 12 n-tiles
  const int tid  = threadIdx.x;
  const int lane = tid & 63, w = tid >> 6;
  const int wm = w >> 1, wn = w & 1;
  const int quad = lane >> 4, l15 = lane & 15;
  const int sw0 = ((quad)     ^ (l15 & 7)) * 8;
  const int sw1 = ((quad + 4) ^ (l15 & 7)) * 8;

  const int ar = tid >> 1;        // A-staging: row 0..127
  const int ah = tid & 1;         // col half (32 f32)
  const float* xrow = x + (size_t)(m0 + ar) * 512 + ah * 32;

  for (int rep = 0; rep < REP; rep++) {
    f32x4 acc[4][4] = {};
    float4 ra[8];

    // prologue: A(0) regs -> LDS; B(0) gload
#pragma unroll
    for (int j = 0; j < 8; j++) ra[j] = *(const float4*)(xrow + j * 4);
    stage_ld512<128>(wta + (size_t)n0 * 512, B_lds[0], tid);
#pragma unroll
    for (int jc = 0; jc < 4; jc++) {
      u16 tmp[8];
      float4 a = ra[2 * jc], b = ra[2 * jc + 1];
      tmp[0] = f2bf(a.x); tmp[1] = f2bf(a.y); tmp[2] = f2bf(a.z); tmp[3] = f2bf(a.w);
      tmp[4] = f2bf(b.x); tmp[5] = f2bf(b.y); tmp[6] = f2bf(b.z); tmp[7] = f2bf(b.w);
      int c = ah * 4 + jc;
      *(uint4*)&A_lds[ar * 64 + (c ^ (ar & 7)) * 8] = *(uint4*)tmp;
    }
    __syncthreads();

    for (int kt = 0; kt < 8; kt++) {
      if (kt < 7) {
#pragma unroll
        for (int j = 0; j < 8; j++) ra[j] = *(const float4*)(xrow + (kt + 1) * 64 + j * 4);
        stage_ld512<128>(wta + (size_t)n0 * 512 + (kt + 1) * 64, B_lds[(kt + 1) & 1], tid);
      }
      const u16* Bb = B_lds[kt & 1];
#pragma unroll
      for (int ks = 0; ks < 2; ks++) {
        const int sw = ks ? sw1 : sw0;
        bf16x8 af[4], bf[4];
#pragma unroll
        for (int ri = 0; ri < 4; ri++)
          af[ri] = *(const bf16x8*)&A_lds[(wm * 64 + ri * 16 + l15) * 64 + sw];
#pragma unroll
        for (int ci = 0; ci < 4; ci++)
          bf[ci] = *(const bf16x8*)&Bb[(wn * 64 + ci * 16 + l15) * 64 + sw];
#pragma unroll
        for (int ri = 0; ri < 4; ri++)
#pragma unroll
          for (int ci = 0; ci < 4; ci++)
            acc[ri][ci] = MFMA16(af[ri], bf[ci], acc[ri][ci]);
      }
      __syncthreads();   // all waves done reading A_lds/B[kt]; prefetches ~landed
      if (kt < 7) {
#pragma unroll
        for (int jc = 0; jc < 4; jc++) {
          u16 tmp[8];
          float4 a = ra[2 * jc], b = ra[2 * jc + 1];
          tmp[0] = f2bf(a.x); tmp[1] = f2bf(a.y); tmp[2] = f2bf(a.z); tmp[3] = f2bf(a.w);
          tmp[4] = f2bf(b.x); tmp[5] = f2bf(b.y); tmp[6] = f2bf(b.z); tmp[7] = f2bf(b.w);
          int c = ah * 4 + jc;
          *(uint4*)&A_lds[ar * 64 + (c ^ (ar & 7)) * 8] = *(uint4*)tmp;
        }
        __syncthreads(); // A visible for next step
      }
    }

    const float QS = 0.18033688011112043f;  // 0.125 * log2(e)
#pragma unroll
    for (int ri = 0; ri < 4; ri++) {
#pragma unroll
      for (int ci = 0; ci < 4; ci++) {
        int n = n0 + wn * 64 + ci * 16 + l15;
        float bias = b_attn[n];
        int chunk = n >> 9;
        int c = n & 511;
        int h = c >> 6, d = c & 63;
        int m_base = m0 + wm * 64 + ri * 16 + quad * 4;
        int b = m_base >> 11, t0 = m_base & 2047;
        int bh = b * 8 + h;
        if (chunk == 0) {
#pragma unroll
          for (int r = 0; r < 4; r++)
            q[(size_t)(bh * 2048 + t0 + r) * 64 + d] = f2bf((acc[ri][ci][r] + bias) * QS);
        } else if (chunk == 1) {
#pragma unroll
          for (int r = 0; r < 4; r++)
            kk[(size_t)(bh * 2048 + t0 + r) * 64 + d] = f2bf(acc[ri][ci][r] + bias);
        } else {
          int it = t0 >> 7, ks2 = (t0 >> 5) & 3, qd = (t0 >> 3) & 3, jj = t0 & 7;
          ushort4 pk;
          pk.x = f2bf(acc[ri][ci][0] + bias);
          pk.y = f2bf(acc[ri][ci][1] + bias);
          pk.z = f2bf(acc[ri][ci][2] + bias);
          pk.w = f2bf(acc[ri][ci][3] + bias);
          size_t idx = ((((size_t)bh * 16 + it) * 4 + ks2) * 64 + d) * 32 + qd * 8 + jj;
          *(ushort4*)&v[idx] = pk;
        }
      }
    }
    asm volatile("" ::: "memory");  // keep reps (block cross-rep DSE)
    __syncthreads();                 // LDS reuse safe across reps
  }
}

// ---------------- flash attention (r1/r3 structure, unchanged) -----------
__global__ __launch_bounds__(256, 4) void flash_attn(const u16* __restrict__ q,
                                                     const u16* __restrict__ k,
                                                     const u16* __restrict__ vt,
                                                     u16* __restrict__ yb) {
  __shared__ u16 K_lds[2][64 * 64];
  __shared__ u16 P_lds[4 * 2 * 16 * 72];  // per-wave 2 x [16 q][64 +pad]

  const int flat = blockIdx.y * 16 + blockIdx.x;
  const int bh = (flat & 7) * 4 + ((flat >> 3) & 3);
  const int qt = flat >> 5;

  const int tid  = threadIdx.x;
  const int lane = tid & 63, w = tid >> 6;
  const int quad = lane >> 4, l15 = lane & 15;
  const int sw0 = ((quad)     ^ (l15 & 7)) * 8;
  const int sw1 = ((quad + 4) ^ (l15 & 7)) * 8;

  const u16* qp = q  + (size_t)bh * 131072;
  const u16* kp = k  + (size_t)bh * 131072;
  const u16* vp = vt + (size_t)bh * 131072;

  bf16x8 qf[2];
#pragma unroll
  for (int ks = 0; ks < 2; ks++)
    qf[ks] = *(const bf16x8*)(qp + (size_t)(qt * 64 + w * 16 + l15) * 64 + ks * 32 + quad * 8);

  f32x4 l_acc = {};
  f32x4 o[4] = {};

  bf16x8 ones;
  {
    short one = (short)0x3F80;
    ones = (bf16x8){one, one, one, one, one, one, one, one};
  }

  u16* Pw = &P_lds[w * 2 * 16 * 72];

#define S_PHASE(KB, PB)                                                        \
  do {                                                                         \
    _Pragma("unroll")                                                          \
    for (int jt = 0; jt < 4; jt++) {                                           \
      bf16x8 kf0 = *(const bf16x8*)&(KB)[(jt * 16 + l15) * 64 + sw0];          \
      bf16x8 kf1 = *(const bf16x8*)&(KB)[(jt * 16 + l15) * 64 + sw1];          \
      f32x4 s = {0.f, 0.f, 0.f, 0.f};                                          \
      s = MFMA16(kf0, qf[0], s);                                               \
      s = MFMA16(kf1, qf[1], s);                                               \
      u32 pb[4];                                                               \
      _Pragma("unroll")                                                        \
      for (int r = 0; r < 4; r++) pb[r] = __float_as_uint(EXP2(s[r]));         \
      uint2 pk;                                                                \
      pk.x = __builtin_amdgcn_perm(pb[1], pb[0], 0x07060302u);                 \
      pk.y = __builtin_amdgcn_perm(pb[3], pb[2], 0x07060302u);                 \
      *(uint2*)&(PB)[l15 * 72 + jt * 16 + quad * 4] = pk;                      \
    }                                                                          \
  } while (0)

#define PV_PHASE(VIT, PB)                                                      \
  do {                                                                         \
    bf16x8 vf[2][4];                                                           \
    _Pragma("unroll")                                                          \
    for (int dt = 0; dt < 4; dt++)                                             \
      vf[0][dt] = *(const bf16x8*)((VIT) + (dt * 16 + l15) * 32 + quad * 8);   \
    _Pragma("unroll")                                                          \
    for (int dt = 0; dt < 4; dt++)                                             \
      vf[1][dt] = *(const bf16x8*)((VIT) + 2048 + (dt * 16 + l15) * 32 + quad * 8); \
    __builtin_amdgcn_s_setprio(1);                                             \
    _Pragma("unroll")                                                          \
    for (int ks = 0; ks < 2; ks++) {                                           \
      bf16x8 pf = *(const bf16x8*)&(PB)[l15 * 72 + ks * 32 + quad * 8];        \
      l_acc = MFMA16(pf, ones, l_acc);                                         \
      _Pragma("unroll")                                                        \
      for (int dt = 0; dt < 4; dt++)                                           \
        o[dt] = MFMA16(pf, vf[ks][dt], o[dt]);                                 \
    }                                                                          \
    __builtin_amdgcn_s_setprio(0);                                             \
  } while (0)

  stage_sw64(kp, K_lds[0], tid);
  stage_sw64(kp + 4096, K_lds[1], tid);
  __syncthreads();
  S_PHASE(K_lds[0], Pw);

  for (int it = 0; it < 31; it++) {
    __syncthreads();
    if (it < 30) stage_sw64(kp + (size_t)(it + 2) * 4096, K_lds[it & 1], tid);
    u16* Pc = Pw + (it & 1) * 16 * 72;
    u16* Pn = Pw + ((it + 1) & 1) * 16 * 72;
    S_PHASE(K_lds[(it + 1) & 1], Pn);
    PV_PHASE(vp + (it) * 4096, Pc);
  }
  PV_PHASE(vp + 31 * 4096, Pw + (31 & 1) * 16 * 72);

#undef S_PHASE
#undef PV_PHASE

  const int b = bh >> 3, h = bh & 7;
  u32* Tw = (u32*)Pw;
#pragma unroll
  for (int r = 0; r < 4; r++) {
    float inv = 1.f / l_acc[r];
#pragma unroll
    for (int dt = 0; dt < 4; dt++) {
      float val = o[dt][r] * inv;
      u16 hi = f2bf(val);
      u16 lo = f2bf(val - bf2f(hi));
      Tw[(quad * 4 + r) * 68 + dt * 16 + l15] = (u32)hi | ((u32)lo << 16);
    }
  }
  {
    int t = qt * 64 + w * 16 + l15;
    size_t rowb = (size_t)(b * 2048 + t) * 512 + h * 64 + quad * 16;
    uint4 g0 = *(uint4*)&Tw[l15 * 68 + quad * 16 + 0];
    uint4 g1 = *(uint4*)&Tw[l15 * 68 + quad * 16 + 4];
    uint4 g2 = *(uint4*)&Tw[l15 * 68 + quad * 16 + 8];
    uint4 g3 = *(uint4*)&Tw[l15 * 68 + quad * 16 + 12];
    uint4 hi4, lo4;
    hi4.x = __builtin_amdgcn_perm(g0.y, g0.x, 0x05040100u);
    hi4.y = __builtin_amdgcn_perm(g0.w, g0.z, 0x05040100u);
    hi4.z = __builtin_amdgcn_perm(g1.y, g1.x, 0x05040100u);
    hi4.w = __builtin_amdgcn_perm(g1.w, g1.z, 0x05040100u);
    lo4.x = __builtin_amdgcn_perm(g0.y, g0.x, 0x07060302u);
    lo4.y = __builtin_amdgcn_perm(g0.w, g0.z, 0x07060302u);
    lo4.z = __builtin_amdgcn_perm(g1.y, g1.x, 0x07060302u);
    lo4.w = __builtin_amdgcn_perm(g1.w, g1.z, 0x07060302u);
    *(uint4*)&yb[rowb] = hi4;
    *(uint4*)&yb[(size_t)4 * 2048 * 512 + rowb] = lo4;
    hi4.x = __builtin_amdgcn_perm(g2.y, g2.x, 0x05040100u);
    hi4.y = __builtin_amdgcn_perm(g2.w, g2.z, 0x05040100u);
    hi4.z = __builtin_amdgcn_perm(g3.y, g3.x, 0x05040100u);
    hi4.w = __builtin_amdgcn_perm(g3.w, g3.z, 0x05040100u);
    lo4.x = __builtin_amdgcn_perm(g2.y, g2.x, 0x07060302u);
    lo4.y = __builtin_amdgcn_perm(g2.w, g2.z, 0x07060302u);
    lo4.z = __builtin_amdgcn_perm(g3.y, g3.x, 0x07060302u);
    lo4.w = __builtin_amdgcn_perm(g3.w, g3.z, 0x07060302u);
    *(uint4*)&yb[rowb + 8] = hi4;
    *(uint4*)&yb[(size_t)4 * 2048 * 512 + rowb + 8] = lo4;
  }
}

// ---------------- output projection (64x64 tile, 2-phase dbuf, REP'd) ----
__global__ __launch_bounds__(256) void gemm_out(const u16* __restrict__ yhi,
                                                const u16* __restrict__ ylo,
                                                const u16* __restrict__ whi,
                                                const u16* __restrict__ wlo,
                                                const float* __restrict__ b_out,
                                                float* __restrict__ out) {
  __shared__ u16 Ah[2][64 * 64];
  __shared__ u16 Al[2][64 * 64];
  __shared__ u16 Bh[2][64 * 64];
  __shared__ u16 Bl[2][64 * 64];
  const int bid = blockIdx.x;
  const int xcd = bid & 7, rr = bid >> 3;
  const int m0 = (xcd * 16 + (rr & 15)) * 64;
  const int n0 = (rr >> 4) * 64;
  const int tid  = threadIdx.x;
  const int lane = tid & 63, w = tid >> 6;
  const int wm = w >> 1, wn = w & 1;
  const int quad = lane >> 4, l15 = lane & 15;
  const int sw0 = ((quad)     ^ (l15 & 7)) * 8;
  const int sw1 = ((quad + 4) ^ (l15 & 7)) * 8;

  for (int rep = 0; rep < REP; rep++) {
    f32x4 acc[2][2] = {};

    stage_ld512<64>(yhi + (size_t)m0 * 512, Ah[0], tid);
    stage_ld512<64>(ylo + (size_t)m0 * 512, Al[0], tid);
    stage_ld512<64>(whi + (size_t)n0 * 512, Bh[0], tid);
    stage_ld512<64>(wlo + (size_t)n0 * 512, Bl[0], tid);
    __syncthreads();

    for (int kt = 0; kt < 8; kt++) {
      const int cur = kt & 1;
      if (kt < 7) {
        const int nxt = cur ^ 1, k0 = (kt + 1) * 64;
        stage_ld512<64>(yhi + (size_t)m0 * 512 + k0, Ah[nxt], tid);
        stage_ld512<64>(ylo + (size_t)m0 * 512 + k0, Al[nxt], tid);
        stage_ld512<64>(whi + (size_t)n0 * 512 + k0, Bh[nxt], tid);
        stage_ld512<64>(wlo + (size_t)n0 * 512 + k0, Bl[nxt], tid);
      }
#pragma unroll
      for (int ks = 0; ks < 2; ks++) {
        const int sw = ks ? sw1 : sw0;
        bf16x8 afh[2], afl[2], bfh[2], bfl[2];
#pragma unroll
        for (int ri = 0; ri < 2; ri++) {
          afh[ri] = *(const bf16x8*)&Ah[cur][(wm * 32 + ri * 16 + l15) * 64 + sw];
          afl[ri] = *(const bf16x8*)&Al[cur][(wm * 32 + ri * 16 + l15) * 64 + sw];
        }
#pragma unroll
        for (int ci = 0; ci < 2; ci++) {
          bfh[ci] = *(const bf16x8*)&Bh[cur][(wn * 32 + ci * 16 + l15) * 64 + sw];
          bfl[ci] = *(const bf16x8*)&Bl[cur][(wn * 32 + ci * 16 + l15) * 64 + sw];
        }
#pragma unroll
        for (int ri = 0; ri < 2; ri++)
#pragma unroll
          for (int ci = 0; ci < 2; ci++) {
            acc[ri][ci] = MFMA16(afh[ri], bfh[ci], acc[ri][ci]);
            acc[ri][ci] = MFMA16(afh[ri], bfl[ci], acc[ri][ci]);
            acc[ri][ci] = MFMA16(afl[ri], bfh[ci], acc[ri][ci]);
          }
      }
      __syncthreads();
    }

#pragma unroll
    for (int ri = 0; ri < 2; ri++) {
#pragma unroll
      for (int ci = 0; ci < 2; ci++) {
        int n = n0 + wn * 32 + ci * 16 + l15;
        float bias = b_out[n];
#pragma unroll
        for (int r = 0; r < 4; r++) {
          int m = m0 + wm * 32 + ri * 16 + quad * 4 + r;
          out[(size_t)m * 512 + n] = acc[ri][ci][r] + bias;
        }
      }
    }
    asm volatile("" ::: "memory");  // keep reps (block cross-rep DSE)
    __syncthreads();                 // LDS reuse safe across reps
  }
}

// ---------------- launch ----------------
extern "C" void kernel_launch(void* const* d_in, const int* in_sizes, int n_in,
                              void* d_out, int out_size, void* d_ws, size_t ws_size,
                              hipStream_t stream) {
  const float* x      = (const float*)d_in[0];
  const float* W_attn = (const float*)d_in[1];
  const float* b_attn = (const float*)d_in[2];
  const float* W_out  = (const float*)d_in[3];
  const float* b_out  = (const float*)d_in[4];
  float* out = (float*)d_out;

  char* ws = (char*)d_ws;
  u16* wta  = (u16*)(ws + 8388608);           //  1.5MB [1536][512]
  u16* wtoh = (u16*)(ws + 9961472);           //  0.5MB [512][512]
  u16* wtol = (u16*)(ws + 10485760);          //  0.5MB
  u16* qb   = (u16*)(ws + 11010048);          //  8 MB  [bh][t][64] (pre-scaled)
  u16* kb   = (u16*)(ws + 19398656);          //  8 MB  [bh][t][64]
  u16* vtb  = (u16*)(ws + 27787264);          //  8 MB  V' frag-packed
  u16* yhi  = (u16*)(ws + 36175872);          //  8 MB  [B,T,C] (+8 MB lo plane)

  prep_kernel<<<256, 256, 0, stream>>>(W_attn, wta, W_out, wtoh, wtol);
  gemm_qkv<<<768, 256, 0, stream>>>(x, wta, b_attn, qb, kb, vtb);
  flash_attn<<<dim3(16, 64), 256, 0, stream>>>(qb, kb, vtb, yhi);
  gemm_out<<<1024, 256, 0, stream>>>(yhi, yhi + (size_t)4 * 2048 * 512, wtoh, wtol, b_out, out);
}

// Round 9
// 199.230 us; speedup vs baseline: 1.5564x; 1.5564x over previous
//
#include <hip/hip_runtime.h>

typedef __attribute__((ext_vector_type(8))) short bf16x8;
typedef __attribute__((ext_vector_type(4))) float f32x4;
typedef unsigned short u16;
typedef unsigned int u32;

#define MFMA16(A, B, C) __builtin_amdgcn_mfma_f32_16x16x32_bf16((A), (B), (C), 0, 0, 0)

#if __has_builtin(__builtin_amdgcn_exp2f)
#define EXP2(x) __builtin_amdgcn_exp2f(x)
#else
#define EXP2(x) exp2f(x)
#endif

typedef __attribute__((address_space(3))) unsigned int lds_u32;
typedef const __attribute__((address_space(1))) unsigned int glb_u32;

__device__ __forceinline__ u16 f2bf(float f) {
  union { float f; unsigned u; } x; x.f = f;
  unsigned r = (x.u + 0x7fffu + ((x.u >> 16) & 1u)) >> 16;
  return (u16)r;
}
__device__ __forceinline__ float bf2f(u16 h) {
  union { float f; unsigned u; } x; x.u = ((unsigned)h) << 16;
  return x.f;
}

// stage a 64x64 bf16 tile (ld=64) into contiguous LDS via global_load_lds,
// XOR-swizzled: LDS slot (row, c) holds global chunk c^(row&7).
__device__ __forceinline__ void stage_sw64(const u16* src, u16* lds, int tid) {
#pragma unroll
  for (int i = 0; i < 2; i++) {
    int vv = tid + i * 256;
    int row = vv >> 3, c = vv & 7;
    const u16* gp = src + (size_t)row * 64 + (size_t)(c ^ (row & 7)) * 8;
    __builtin_amdgcn_global_load_lds((glb_u32*)gp,
        (lds_u32*)(lds + (size_t)(i * 256 + (tid & 192)) * 8), 16, 0, 0);
  }
}

// stage ROWS x 64 bf16 tile from a row-major [*][512] matrix (ld=512) into
// contiguous LDS, same XOR swizzle.
template <int ROWS>
__device__ __forceinline__ void stage_ld512(const u16* src, u16* lds, int tid) {
#pragma unroll
  for (int i = 0; i < ROWS / 32; i++) {
    int vv = tid + i * 256;
    int row = vv >> 3, c = vv & 7;
    const u16* gp = src + (size_t)row * 512 + (size_t)(c ^ (row & 7)) * 8;
    __builtin_amdgcn_global_load_lds((glb_u32*)gp,
        (lds_u32*)(lds + (size_t)(i * 256 + (tid & 192)) * 8), 16, 0, 0);
  }
}

// ---------------- prep kernel (transposes only; cast folded into qkv) ----
// blocks [0,192): W_attn [512][1536] -> wta [1536][512] bf16
// blocks [192,256): W_out [512][512] -> whi/wlo transposed hi/lo
__global__ __launch_bounds__(256) void prep_kernel(const float* __restrict__ Wa,
                                                   u16* __restrict__ wta,
                                                   const float* __restrict__ Wo,
                                                   u16* __restrict__ whi,
                                                   u16* __restrict__ wlo) {
  __shared__ u16 Th[64][72];
  __shared__ u16 Tl[64][72];
  const int bid = blockIdx.x;
  const int tid = threadIdx.x;

  if (bid < 192) {
    const int t = bid;
    const int n0 = (t % 24) * 64;
    const int k0 = (t / 24) * 64;
    const int r = tid >> 4, c4 = (tid & 15) * 4;
#pragma unroll
    for (int i = 0; i < 4; i++) {
      int row = r + i * 16;
      float4 v = *(const float4*)&Wa[(size_t)(k0 + row) * 1536 + n0 + c4];
      Th[c4 + 0][row] = f2bf(v.x);
      Th[c4 + 1][row] = f2bf(v.y);
      Th[c4 + 2][row] = f2bf(v.z);
      Th[c4 + 3][row] = f2bf(v.w);
    }
    __syncthreads();
    const int row = tid >> 2, c16 = (tid & 3) * 16;
    *(uint4*)&wta[(size_t)(n0 + row) * 512 + k0 + c16]     = *(uint4*)&Th[row][c16];
    *(uint4*)&wta[(size_t)(n0 + row) * 512 + k0 + c16 + 8] = *(uint4*)&Th[row][c16 + 8];
    return;
  }

  {
    const int t = bid - 192;
    const int n0 = (t & 7) * 64;
    const int k0 = (t >> 3) * 64;
    const int r = tid >> 4, c4 = (tid & 15) * 4;
#pragma unroll
    for (int i = 0; i < 4; i++) {
      int row = r + i * 16;
      float4 v = *(const float4*)&Wo[(size_t)(k0 + row) * 512 + n0 + c4];
      float vv[4] = {v.x, v.y, v.z, v.w};
#pragma unroll
      for (int jj = 0; jj < 4; jj++) {
        u16 hi = f2bf(vv[jj]);
        Th[c4 + jj][row] = hi;
        Tl[c4 + jj][row] = f2bf(vv[jj] - bf2f(hi));
      }
    }
    __syncthreads();
    const int row = tid >> 2, c16 = (tid & 3) * 16;
    *(uint4*)&whi[(size_t)(n0 + row) * 512 + k0 + c16]     = *(uint4*)&Th[row][c16];
    *(uint4*)&whi[(size_t)(n0 + row) * 512 + k0 + c16 + 8] = *(uint4*)&Th[row][c16 + 8];
    *(uint4*)&wlo[(size_t)(n0 + row) * 512 + k0 + c16]     = *(uint4*)&Tl[row][c16];
    *(uint4*)&wlo[(size_t)(n0 + row) * 512 + k0 + c16 + 8] = *(uint4*)&Tl[row][c16 + 8];
  }
}

// ---------------- QKV GEMM (128x128 tile, cast folded) -------------------
// r7 measured (REP probe): 44 us, MfmaUtil 11.6, bank-conflict 0, WRITE
// amplification 1.8x from the q/k scalar-u16 scatter epilogue. This round:
// q/k epilogue goes through a per-wave 64x72 LDS transpose (chunk/head are
// wave-uniform; d spans 0..63) -> each lane stores one full 128B row as
// 8x uint4, fully coalesced. V' path unchanged.
// NOTE: no LDS pointer arrays (r8 compile fail: addrspacecast static init);
// buffer selection is inline offset arithmetic.
__global__ __launch_bounds__(256, 3) void gemm_qkv(const float* __restrict__ x,
                                                   const u16* __restrict__ wta,
                                                   const float* __restrict__ b_attn,
                                                   u16* __restrict__ q,
                                                   u16* __restrict__ kk,
                                                   u16* __restrict__ v) {
  // Layout: [0,8192) = A, [8192,16384) = B buf0, [16384,24576) = B buf1.
  // Epilogue reuses the front 4 x 4608 u16 as per-wave transpose scratch.
  __shared__ u16 Smem[3 * 128 * 64];

  const int bid = blockIdx.x;
  const int xcd = bid & 7, rr = bid >> 3;       // rr in [0,96)
  const int m0 = (xcd * 8 + (rr & 7)) * 128;    // 64 m-tiles
  const int n0 = (rr >> 3) * 128;               // 12 n-tiles
  const int tid  = threadIdx.x;
  const int lane = tid & 63, w = tid >> 6;
  const int wm = w >> 1, wn = w & 1;
  const int quad = lane >> 4, l15 = lane & 15;
  const int sw0 = ((quad)     ^ (l15 & 7)) * 8;
  const int sw1 = ((quad + 4) ^ (l15 & 7)) * 8;

  const int ar = tid >> 1;        // A-staging: row 0..127
  const int ah = tid & 1;         // col half (32 f32)
  const float* xrow = x + (size_t)(m0 + ar) * 512 + ah * 32;

  f32x4 acc[4][4] = {};
  float4 ra[8];

  // prologue: A(0) regs -> LDS; B(0) gload
#pragma unroll
  for (int j = 0; j < 8; j++) ra[j] = *(const float4*)(xrow + j * 4);
  stage_ld512<128>(wta + (size_t)n0 * 512, Smem + 8192, tid);
#pragma unroll
  for (int jc = 0; jc < 4; jc++) {
    u16 tmp[8];
    float4 a = ra[2 * jc], b = ra[2 * jc + 1];
    tmp[0] = f2bf(a.x); tmp[1] = f2bf(a.y); tmp[2] = f2bf(a.z); tmp[3] = f2bf(a.w);
    tmp[4] = f2bf(b.x); tmp[5] = f2bf(b.y); tmp[6] = f2bf(b.z); tmp[7] = f2bf(b.w);
    int c = ah * 4 + jc;
    *(uint4*)&Smem[ar * 64 + (c ^ (ar & 7)) * 8] = *(uint4*)tmp;
  }
  __syncthreads();

  for (int kt = 0; kt < 8; kt++) {
    if (kt < 7) {
#pragma unroll
      for (int j = 0; j < 8; j++) ra[j] = *(const float4*)(xrow + (kt + 1) * 64 + j * 4);
      stage_ld512<128>(wta + (size_t)n0 * 512 + (kt + 1) * 64,
                       Smem + 8192 + ((kt + 1) & 1) * 8192, tid);
    }
    const u16* Bb = Smem + 8192 + (kt & 1) * 8192;
#pragma unroll
    for (int ks = 0; ks < 2; ks++) {
      const int sw = ks ? sw1 : sw0;
      bf16x8 af[4], bf[4];
#pragma unroll
      for (int ri = 0; ri < 4; ri++)
        af[ri] = *(const bf16x8*)&Smem[(wm * 64 + ri * 16 + l15) * 64 + sw];
#pragma unroll
      for (int ci = 0; ci < 4; ci++)
        bf[ci] = *(const bf16x8*)&Bb[(wn * 64 + ci * 16 + l15) * 64 + sw];
#pragma unroll
      for (int ri = 0; ri < 4; ri++)
#pragma unroll
        for (int ci = 0; ci < 4; ci++)
          acc[ri][ci] = MFMA16(af[ri], bf[ci], acc[ri][ci]);
    }
    __syncthreads();   // all waves done reading A/B[kt]; prefetches ~landed
    if (kt < 7) {
#pragma unroll
      for (int jc = 0; jc < 4; jc++) {
        u16 tmp[8];
        float4 a = ra[2 * jc], b = ra[2 * jc + 1];
        tmp[0] = f2bf(a.x); tmp[1] = f2bf(a.y); tmp[2] = f2bf(a.z); tmp[3] = f2bf(a.w);
        tmp[4] = f2bf(b.x); tmp[5] = f2bf(b.y); tmp[6] = f2bf(b.z); tmp[7] = f2bf(b.w);
        int c = ah * 4 + jc;
        *(uint4*)&Smem[ar * 64 + (c ^ (ar & 7)) * 8] = *(uint4*)tmp;
      }
      __syncthreads(); // A visible for next step
    }
  }

  // ---------------- epilogue ----------------
  // chunk / head / batch are wave-uniform (wave n-range is 64-wide and
  // 64-aligned; m-range is 64-wide within one batch block).
  const float QS = 0.18033688011112043f;  // 0.125 * log2(e)
  const int wave_n0 = n0 + wn * 64;
  const int chunk = wave_n0 >> 9;
  const int h = (wave_n0 & 511) >> 6;
  const int m_wave = m0 + wm * 64;
  const int b = m_wave >> 11, t0 = m_wave & 2047;
  const int bh = b * 8 + h;

  if (chunk < 2) {
    // q/k: per-wave LDS transpose -> fully coalesced 128B-row stores
    u16* T = Smem + w * 4608;  // 64 x 72 per-wave scratch
    u16* dst = (chunk == 0) ? q : kk;
    const float scale = (chunk == 0) ? QS : 1.0f;
#pragma unroll
    for (int ri = 0; ri < 4; ri++)
#pragma unroll
      for (int ci = 0; ci < 4; ci++) {
        float bias = b_attn[wave_n0 + ci * 16 + l15];
#pragma unroll
        for (int r = 0; r < 4; r++) {
          int tl = ri * 16 + quad * 4 + r;
          T[tl * 72 + ci * 16 + l15] = f2bf((acc[ri][ci][r] + bias) * scale);
        }
      }
    // same-wave LDS RAW (compiler inserts lgkmcnt); per-wave scratch disjoint
    u16* gdst = dst + (size_t)(bh * 2048 + t0 + lane) * 64;
#pragma unroll
    for (int j = 0; j < 8; j++)
      *(uint4*)&gdst[j * 8] = *(const uint4*)&T[lane * 72 + j * 8];
  } else {
    // V': frag-packed layout (ushort4 stores, line-filling across frags)
#pragma unroll
    for (int ri = 0; ri < 4; ri++)
#pragma unroll
      for (int ci = 0; ci < 4; ci++) {
        int n = wave_n0 + ci * 16 + l15;
        float bias = b_attn[n];
        int d = n & 63;
        int tv = t0 + ri * 16 + quad * 4;
        int it = tv >> 7, ks2 = (tv >> 5) & 3, qd = (tv >> 3) & 3, jj = tv & 7;
        ushort4 pk;
        pk.x = f2bf(acc[ri][ci][0] + bias);
        pk.y = f2bf(acc[ri][ci][1] + bias);
        pk.z = f2bf(acc[ri][ci][2] + bias);
        pk.w = f2bf(acc[ri][ci][3] + bias);
        size_t idx = ((((size_t)bh * 16 + it) * 4 + ks2) * 64 + d) * 32 + qd * 8 + jj;
        *(ushort4*)&v[idx] = pk;
      }
  }
}

// ---------------- flash attention (r1/r3 structure, unchanged) -----------
__global__ __launch_bounds__(256, 4) void flash_attn(const u16* __restrict__ q,
                                                     const u16* __restrict__ k,
                                                     const u16* __restrict__ vt,
                                                     u16* __restrict__ yb) {
  __shared__ u16 K_lds[2][64 * 64];
  __shared__ u16 P_lds[4 * 2 * 16 * 72];  // per-wave 2 x [16 q][64 +pad]

  const int flat = blockIdx.y * 16 + blockIdx.x;
  const int bh = (flat & 7) * 4 + ((flat >> 3) & 3);
  const int qt = flat >> 5;

  const int tid  = threadIdx.x;
  const int lane = tid & 63, w = tid >> 6;
  const int quad = lane >> 4, l15 = lane & 15;
  const int sw0 = ((quad)     ^ (l15 & 7)) * 8;
  const int sw1 = ((quad + 4) ^ (l15 & 7)) * 8;

  const u16* qp = q  + (size_t)bh * 131072;
  const u16* kp = k  + (size_t)bh * 131072;
  const u16* vp = vt + (size_t)bh * 131072;

  bf16x8 qf[2];
#pragma unroll
  for (int ks = 0; ks < 2; ks++)
    qf[ks] = *(const bf16x8*)(qp + (size_t)(qt * 64 + w * 16 + l15) * 64 + ks * 32 + quad * 8);

  f32x4 l_acc = {};
  f32x4 o[4] = {};

  bf16x8 ones;
  {
    short one = (short)0x3F80;
    ones = (bf16x8){one, one, one, one, one, one, one, one};
  }

  u16* Pw = &P_lds[w * 2 * 16 * 72];

#define S_PHASE(KB, PB)                                                        \
  do {                                                                         \
    _Pragma("unroll")                                                          \
    for (int jt = 0; jt < 4; jt++) {                                           \
      bf16x8 kf0 = *(const bf16x8*)&(KB)[(jt * 16 + l15) * 64 + sw0];          \
      bf16x8 kf1 = *(const bf16x8*)&(KB)[(jt * 16 + l15) * 64 + sw1];          \
      f32x4 s = {0.f, 0.f, 0.f, 0.f};                                          \
      s = MFMA16(kf0, qf[0], s);                                               \
      s = MFMA16(kf1, qf[1], s);                                               \
      u32 pb[4];                                                               \
      _Pragma("unroll")                                                        \
      for (int r = 0; r < 4; r++) pb[r] = __float_as_uint(EXP2(s[r]));         \
      uint2 pk;                                                                \
      pk.x = __builtin_amdgcn_perm(pb[1], pb[0], 0x07060302u);                 \
      pk.y = __builtin_amdgcn_perm(pb[3], pb[2], 0x07060302u);                 \
      *(uint2*)&(PB)[l15 * 72 + jt * 16 + quad * 4] = pk;                      \
    }                                                                          \
  } while (0)

#define PV_PHASE(VIT, PB)                                                      \
  do {                                                                         \
    bf16x8 vf[2][4];                                                           \
    _Pragma("unroll")                                                          \
    for (int dt = 0; dt < 4; dt++)                                             \
      vf[0][dt] = *(const bf16x8*)((VIT) + (dt * 16 + l15) * 32 + quad * 8);   \
    _Pragma("unroll")                                                          \
    for (int dt = 0; dt < 4; dt++)                                             \
      vf[1][dt] = *(const bf16x8*)((VIT) + 2048 + (dt * 16 + l15) * 32 + quad * 8); \
    __builtin_amdgcn_s_setprio(1);                                             \
    _Pragma("unroll")                                                          \
    for (int ks = 0; ks < 2; ks++) {                                           \
      bf16x8 pf = *(const bf16x8*)&(PB)[l15 * 72 + ks * 32 + quad * 8];        \
      l_acc = MFMA16(pf, ones, l_acc);                                         \
      _Pragma("unroll")                                                        \
      for (int dt = 0; dt < 4; dt++)                                           \
        o[dt] = MFMA16(pf, vf[ks][dt], o[dt]);                                 \
    }                                                                          \
    __builtin_amdgcn_s_setprio(0);                                             \
  } while (0)

  stage_sw64(kp, K_lds[0], tid);
  stage_sw64(kp + 4096, K_lds[1], tid);
  __syncthreads();
  S_PHASE(K_lds[0], Pw);

  for (int it = 0; it < 31; it++) {
    __syncthreads();
    if (it < 30) stage_sw64(kp + (size_t)(it + 2) * 4096, K_lds[it & 1], tid);
    u16* Pc = Pw + (it & 1) * 16 * 72;
    u16* Pn = Pw + ((it + 1) & 1) * 16 * 72;
    S_PHASE(K_lds[(it + 1) & 1], Pn);
    PV_PHASE(vp + (it) * 4096, Pc);
  }
  PV_PHASE(vp + 31 * 4096, Pw + (31 & 1) * 16 * 72);

#undef S_PHASE
#undef PV_PHASE

  const int b = bh >> 3, h = bh & 7;
  u32* Tw = (u32*)Pw;
#pragma unroll
  for (int r = 0; r < 4; r++) {
    float inv = 1.f / l_acc[r];
#pragma unroll
    for (int dt = 0; dt < 4; dt++) {
      float val = o[dt][r] * inv;
      u16 hi = f2bf(val);
      u16 lo = f2bf(val - bf2f(hi));
      Tw[(quad * 4 + r) * 68 + dt * 16 + l15] = (u32)hi | ((u32)lo << 16);
    }
  }
  {
    int t = qt * 64 + w * 16 + l15;
    size_t rowb = (size_t)(b * 2048 + t) * 512 + h * 64 + quad * 16;
    uint4 g0 = *(uint4*)&Tw[l15 * 68 + quad * 16 + 0];
    uint4 g1 = *(uint4*)&Tw[l15 * 68 + quad * 16 + 4];
    uint4 g2 = *(uint4*)&Tw[l15 * 68 + quad * 16 + 8];
    uint4 g3 = *(uint4*)&Tw[l15 * 68 + quad * 16 + 12];
    uint4 hi4, lo4;
    hi4.x = __builtin_amdgcn_perm(g0.y, g0.x, 0x05040100u);
    hi4.y = __builtin_amdgcn_perm(g0.w, g0.z, 0x05040100u);
    hi4.z = __builtin_amdgcn_perm(g1.y, g1.x, 0x05040100u);
    hi4.w = __builtin_amdgcn_perm(g1.w, g1.z, 0x05040100u);
    lo4.x = __builtin_amdgcn_perm(g0.y, g0.x, 0x07060302u);
    lo4.y = __builtin_amdgcn_perm(g0.w, g0.z, 0x07060302u);
    lo4.z = __builtin_amdgcn_perm(g1.y, g1.x, 0x07060302u);
    lo4.w = __builtin_amdgcn_perm(g1.w, g1.z, 0x07060302u);
    *(uint4*)&yb[rowb] = hi4;
    *(uint4*)&yb[(size_t)4 * 2048 * 512 + rowb] = lo4;
    hi4.x = __builtin_amdgcn_perm(g2.y, g2.x, 0x05040100u);
    hi4.y = __builtin_amdgcn_perm(g2.w, g2.z, 0x05040100u);
    hi4.z = __builtin_amdgcn_perm(g3.y, g3.x, 0x05040100u);
    hi4.w = __builtin_amdgcn_perm(g3.w, g3.z, 0x05040100u);
    lo4.x = __builtin_amdgcn_perm(g2.y, g2.x, 0x07060302u);
    lo4.y = __builtin_amdgcn_perm(g2.w, g2.z, 0x07060302u);
    lo4.z = __builtin_amdgcn_perm(g3.y, g3.x, 0x07060302u);
    lo4.w = __builtin_amdgcn_perm(g3.w, g3.z, 0x07060302u);
    *(uint4*)&yb[rowb + 8] = hi4;
    *(uint4*)&yb[(size_t)4 * 2048 * 512 + rowb + 8] = lo4;
  }
}

// ---------------- output projection (64x64 tile, 2-phase dbuf) -----------
__global__ __launch_bounds__(256) void gemm_out(const u16* __restrict__ yhi,
                                                const u16* __restrict__ ylo,
                                                const u16* __restrict__ whi,
                                                const u16* __restrict__ wlo,
                                                const float* __restrict__ b_out,
                                                float* __restrict__ out) {
  __shared__ u16 Ah[2][64 * 64];
  __shared__ u16 Al[2][64 * 64];
  __shared__ u16 Bh[2][64 * 64];
  __shared__ u16 Bl[2][64 * 64];
  const int bid = blockIdx.x;
  const int xcd = bid & 7, rr = bid >> 3;
  const int m0 = (xcd * 16 + (rr & 15)) * 64;
  const int n0 = (rr >> 4) * 64;
  const int tid  = threadIdx.x;
  const int lane = tid & 63, w = tid >> 6;
  const int wm = w >> 1, wn = w & 1;
  const int quad = lane >> 4, l15 = lane & 15;
  const int sw0 = ((quad)     ^ (l15 & 7)) * 8;
  const int sw1 = ((quad + 4) ^ (l15 & 7)) * 8;

  f32x4 acc[2][2] = {};

  stage_ld512<64>(yhi + (size_t)m0 * 512, Ah[0], tid);
  stage_ld512<64>(ylo + (size_t)m0 * 512, Al[0], tid);
  stage_ld512<64>(whi + (size_t)n0 * 512, Bh[0], tid);
  stage_ld512<64>(wlo + (size_t)n0 * 512, Bl[0], tid);
  __syncthreads();

  for (int kt = 0; kt < 8; kt++) {
    const int cur = kt & 1;
    if (kt < 7) {
      const int nxt = cur ^ 1, k0 = (kt + 1) * 64;
      stage_ld512<64>(yhi + (size_t)m0 * 512 + k0, Ah[nxt], tid);
      stage_ld512<64>(ylo + (size_t)m0 * 512 + k0, Al[nxt], tid);
      stage_ld512<64>(whi + (size_t)n0 * 512 + k0, Bh[nxt], tid);
      stage_ld512<64>(wlo + (size_t)n0 * 512 + k0, Bl[nxt], tid);
    }
#pragma unroll
    for (int ks = 0; ks < 2; ks++) {
      const int sw = ks ? sw1 : sw0;
      bf16x8 afh[2], afl[2], bfh[2], bfl[2];
#pragma unroll
      for (int ri = 0; ri < 2; ri++) {
        afh[ri] = *(const bf16x8*)&Ah[cur][(wm * 32 + ri * 16 + l15) * 64 + sw];
        afl[ri] = *(const bf16x8*)&Al[cur][(wm * 32 + ri * 16 + l15) * 64 + sw];
      }
#pragma unroll
      for (int ci = 0; ci < 2; ci++) {
        bfh[ci] = *(const bf16x8*)&Bh[cur][(wn * 32 + ci * 16 + l15) * 64 + sw];
        bfl[ci] = *(const bf16x8*)&Bl[cur][(wn * 32 + ci * 16 + l15) * 64 + sw];
      }
#pragma unroll
      for (int ri = 0; ri < 2; ri++)
#pragma unroll
        for (int ci = 0; ci < 2; ci++) {
          acc[ri][ci] = MFMA16(afh[ri], bfh[ci], acc[ri][ci]);
          acc[ri][ci] = MFMA16(afh[ri], bfl[ci], acc[ri][ci]);
          acc[ri][ci] = MFMA16(afl[ri], bfh[ci], acc[ri][ci]);
        }
    }
    __syncthreads();
  }

#pragma unroll
  for (int ri = 0; ri < 2; ri++) {
#pragma unroll
    for (int ci = 0; ci < 2; ci++) {
      int n = n0 + wn * 32 + ci * 16 + l15;
      float bias = b_out[n];
#pragma unroll
      for (int r = 0; r < 4; r++) {
        int m = m0 + wm * 32 + ri * 16 + quad * 4 + r;
        out[(size_t)m * 512 + n] = acc[ri][ci][r] + bias;
      }
    }
  }
}

// ---------------- launch ----------------
extern "C" void kernel_launch(void* const* d_in, const int* in_sizes, int n_in,
                              void* d_out, int out_size, void* d_ws, size_t ws_size,
                              hipStream_t stream) {
  const float* x      = (const float*)d_in[0];
  const float* W_attn = (const float*)d_in[1];
  const float* b_attn = (const float*)d_in[2];
  const float* W_out  = (const float*)d_in[3];
  const float* b_out  = (const float*)d_in[4];
  float* out = (float*)d_out;

  char* ws = (char*)d_ws;
  u16* wta  = (u16*)(ws + 8388608);           //  1.5MB [1536][512]
  u16* wtoh = (u16*)(ws + 9961472);           //  0.5MB [512][512]
  u16* wtol = (u16*)(ws + 10485760);          //  0.5MB
  u16* qb   = (u16*)(ws + 11010048);          //  8 MB  [bh][t][64] (pre-scaled)
  u16* kb   = (u16*)(ws + 19398656);          //  8 MB  [bh][t][64]
  u16* vtb  = (u16*)(ws + 27787264);          //  8 MB  V' frag-packed
  u16* yhi  = (u16*)(ws + 36175872);          //  8 MB  [B,T,C] (+8 MB lo plane)

  prep_kernel<<<256, 256, 0, stream>>>(W_attn, wta, W_out, wtoh, wtol);
  gemm_qkv<<<768, 256, 0, stream>>>(x, wta, b_attn, qb, kb, vtb);
  flash_attn<<<dim3(16, 64), 256, 0, stream>>>(qb, kb, vtb, yhi);
  gemm_out<<<1024, 256, 0, stream>>>(yhi, yhi + (size_t)4 * 2048 * 512, wtoh, wtol, b_out, out);
}

// Round 10
// 193.264 us; speedup vs baseline: 1.6045x; 1.0309x over previous
//
#include <hip/hip_runtime.h>

typedef __attribute__((ext_vector_type(8))) short bf16x8;
typedef __attribute__((ext_vector_type(4))) float f32x4;
typedef unsigned short u16;
typedef unsigned int u32;

#define MFMA16(A, B, C) __builtin_amdgcn_mfma_f32_16x16x32_bf16((A), (B), (C), 0, 0, 0)

#if __has_builtin(__builtin_amdgcn_exp2f)
#define EXP2(x) __builtin_amdgcn_exp2f(x)
#else
#define EXP2(x) exp2f(x)
#endif

typedef __attribute__((address_space(3))) unsigned int lds_u32;
typedef const __attribute__((address_space(1))) unsigned int glb_u32;

__device__ __forceinline__ u16 f2bf(float f) {
  union { float f; unsigned u; } x; x.f = f;
  unsigned r = (x.u + 0x7fffu + ((x.u >> 16) & 1u)) >> 16;
  return (u16)r;
}
__device__ __forceinline__ float bf2f(u16 h) {
  union { float f; unsigned u; } x; x.u = ((unsigned)h) << 16;
  return x.f;
}

// stage a 64x64 bf16 tile (ld=64) into contiguous LDS via global_load_lds,
// XOR-swizzled: LDS slot (row, c) holds global chunk c^(row&7).
__device__ __forceinline__ void stage_sw64(const u16* src, u16* lds, int tid) {
#pragma unroll
  for (int i = 0; i < 2; i++) {
    int vv = tid + i * 256;
    int row = vv >> 3, c = vv & 7;
    const u16* gp = src + (size_t)row * 64 + (size_t)(c ^ (row & 7)) * 8;
    __builtin_amdgcn_global_load_lds((glb_u32*)gp,
        (lds_u32*)(lds + (size_t)(i * 256 + (tid & 192)) * 8), 16, 0, 0);
  }
}

// stage ROWS x 64 bf16 tile from a row-major [*][512] matrix (ld=512) into
// contiguous LDS, same XOR swizzle.
template <int ROWS>
__device__ __forceinline__ void stage_ld512(const u16* src, u16* lds, int tid) {
#pragma unroll
  for (int i = 0; i < ROWS / 32; i++) {
    int vv = tid + i * 256;
    int row = vv >> 3, c = vv & 7;
    const u16* gp = src + (size_t)row * 512 + (size_t)(c ^ (row & 7)) * 8;
    __builtin_amdgcn_global_load_lds((glb_u32*)gp,
        (lds_u32*)(lds + (size_t)(i * 256 + (tid & 192)) * 8), 16, 0, 0);
  }
}

// ---------------- fused prep kernel (r5 version — best measured) ---------
// blocks [0,4096): cast x -> xb (bf16)
// blocks [4096,4288): W_attn -> wta [1536][512] bf16 transposed
// blocks [4288,4352): W_out -> whi/wlo transposed hi/lo
__global__ __launch_bounds__(256) void prep_kernel(const float* __restrict__ x,
                                                   u16* __restrict__ xb,
                                                   const float* __restrict__ Wa,
                                                   u16* __restrict__ wta,
                                                   const float* __restrict__ Wo,
                                                   u16* __restrict__ whi,
                                                   u16* __restrict__ wlo) {
  __shared__ u16 Th[64][72];
  __shared__ u16 Tl[64][72];
  const int bid = blockIdx.x;
  const int tid = threadIdx.x;

  if (bid < 4096) {
    int i = bid * 256 + tid;
    float4 v = ((const float4*)x)[i];
    ushort4 o;
    o.x = f2bf(v.x); o.y = f2bf(v.y); o.z = f2bf(v.z); o.w = f2bf(v.w);
    ((ushort4*)xb)[i] = o;
    return;
  }

  if (bid < 4288) {
    const int t = bid - 4096;
    const int n0 = (t % 24) * 64;
    const int k0 = (t / 24) * 64;
    const int r = tid >> 4, c4 = (tid & 15) * 4;
#pragma unroll
    for (int i = 0; i < 4; i++) {
      int row = r + i * 16;
      float4 v = *(const float4*)&Wa[(size_t)(k0 + row) * 1536 + n0 + c4];
      Th[c4 + 0][row] = f2bf(v.x);
      Th[c4 + 1][row] = f2bf(v.y);
      Th[c4 + 2][row] = f2bf(v.z);
      Th[c4 + 3][row] = f2bf(v.w);
    }
    __syncthreads();
    const int row = tid >> 2, c16 = (tid & 3) * 16;
    *(uint4*)&wta[(size_t)(n0 + row) * 512 + k0 + c16]     = *(uint4*)&Th[row][c16];
    *(uint4*)&wta[(size_t)(n0 + row) * 512 + k0 + c16 + 8] = *(uint4*)&Th[row][c16 + 8];
    return;
  }

  {
    const int t = bid - 4288;
    const int n0 = (t & 7) * 64;
    const int k0 = (t >> 3) * 64;
    const int r = tid >> 4, c4 = (tid & 15) * 4;
#pragma unroll
    for (int i = 0; i < 4; i++) {
      int row = r + i * 16;
      float4 v = *(const float4*)&Wo[(size_t)(k0 + row) * 512 + n0 + c4];
      float vv[4] = {v.x, v.y, v.z, v.w};
#pragma unroll
      for (int jj = 0; jj < 4; jj++) {
        u16 hi = f2bf(vv[jj]);
        Th[c4 + jj][row] = hi;
        Tl[c4 + jj][row] = f2bf(vv[jj] - bf2f(hi));
      }
    }
    __syncthreads();
    const int row = tid >> 2, c16 = (tid & 3) * 16;
    *(uint4*)&whi[(size_t)(n0 + row) * 512 + k0 + c16]     = *(uint4*)&Th[row][c16];
    *(uint4*)&whi[(size_t)(n0 + row) * 512 + k0 + c16 + 8] = *(uint4*)&Th[row][c16 + 8];
    *(uint4*)&wlo[(size_t)(n0 + row) * 512 + k0 + c16]     = *(uint4*)&Tl[row][c16];
    *(uint4*)&wlo[(size_t)(n0 + row) * 512 + k0 + c16 + 8] = *(uint4*)&Tl[row][c16 + 8];
  }
}

// ---------------- QKV GEMM (r4 128x128 single-buf + coalesced epilogue) --
// r4/r5 measured best non-flash combo; dbuf (r6) and cast-folding (r9) both
// regressed it. Only change vs r4: q/k epilogue goes through per-wave LDS
// transpose -> coalesced 128B-row stores (r7 PMC: 1.8x WRITE amplification
// from the old scalar scatter). Smem 36 KB: A 16K + B 16K + 4K pad so the
// 4 x (64x72) per-wave scratch tiles fit after the final barrier.
__global__ __launch_bounds__(256) void gemm_qkv(const u16* __restrict__ xb,
                                                const u16* __restrict__ wta,
                                                const float* __restrict__ b_attn,
                                                u16* __restrict__ q,
                                                u16* __restrict__ kk,
                                                u16* __restrict__ v) {
  __shared__ u16 Smem[18432];  // [0,8192)=A, [8192,16384)=B, rest epilogue pad
  const int bid = blockIdx.x;
  const int xcd = bid & 7, rr = bid >> 3;       // rr in [0,96)
  const int m0 = (xcd * 8 + (rr & 7)) * 128;    // 64 m-tiles
  const int n0 = (rr >> 3) * 128;               // 12 n-tiles
  const int tid  = threadIdx.x;
  const int lane = tid & 63, w = tid >> 6;
  const int wm = w >> 1, wn = w & 1;
  const int quad = lane >> 4, l15 = lane & 15;
  const int sw0 = ((quad)     ^ (l15 & 7)) * 8;
  const int sw1 = ((quad + 4) ^ (l15 & 7)) * 8;

  f32x4 acc[4][4] = {};

  for (int kt = 0; kt < 8; kt++) {
    stage_ld512<128>(xb  + (size_t)m0 * 512 + kt * 64, Smem, tid);
    stage_ld512<128>(wta + (size_t)n0 * 512 + kt * 64, Smem + 8192, tid);
    __syncthreads();
#pragma unroll
    for (int ks = 0; ks < 2; ks++) {
      const int sw = ks ? sw1 : sw0;
      bf16x8 af[4], bf[4];
#pragma unroll
      for (int ri = 0; ri < 4; ri++)
        af[ri] = *(const bf16x8*)&Smem[(wm * 64 + ri * 16 + l15) * 64 + sw];
#pragma unroll
      for (int ci = 0; ci < 4; ci++)
        bf[ci] = *(const bf16x8*)&Smem[8192 + (wn * 64 + ci * 16 + l15) * 64 + sw];
#pragma unroll
      for (int ri = 0; ri < 4; ri++)
#pragma unroll
        for (int ci = 0; ci < 4; ci++)
          acc[ri][ci] = MFMA16(af[ri], bf[ci], acc[ri][ci]);
    }
    __syncthreads();
  }

  // ---------------- epilogue ----------------
  // chunk / head / batch are wave-uniform (wave n-range is 64-wide,
  // 64-aligned inside a 128-aligned tile; chunks are 512-wide).
  const float QS = 0.18033688011112043f;  // 0.125 * log2(e)
  const int wave_n0 = n0 + wn * 64;
  const int chunk = wave_n0 >> 9;
  const int h = (wave_n0 & 511) >> 6;
  const int m_wave = m0 + wm * 64;
  const int b = m_wave >> 11, t0 = m_wave & 2047;
  const int bh = b * 8 + h;

  if (chunk < 2) {
    // q/k: per-wave LDS transpose -> fully coalesced 128B-row stores
    u16* T = Smem + w * 4608;  // 64 x 72 per-wave scratch (post-barrier reuse)
    u16* dst = (chunk == 0) ? q : kk;
    const float scale = (chunk == 0) ? QS : 1.0f;
#pragma unroll
    for (int ri = 0; ri < 4; ri++)
#pragma unroll
      for (int ci = 0; ci < 4; ci++) {
        float bias = b_attn[wave_n0 + ci * 16 + l15];
#pragma unroll
        for (int r = 0; r < 4; r++) {
          int tl = ri * 16 + quad * 4 + r;
          T[tl * 72 + ci * 16 + l15] = f2bf((acc[ri][ci][r] + bias) * scale);
        }
      }
    // same-wave LDS RAW (compiler inserts lgkmcnt); per-wave scratch disjoint
    u16* gdst = dst + (size_t)(bh * 2048 + t0 + lane) * 64;
#pragma unroll
    for (int j = 0; j < 8; j++)
      *(uint4*)&gdst[j * 8] = *(const uint4*)&T[lane * 72 + j * 8];
  } else {
    // V': frag-packed layout (ushort4 stores, line-filling across frags)
#pragma unroll
    for (int ri = 0; ri < 4; ri++)
#pragma unroll
      for (int ci = 0; ci < 4; ci++) {
        int n = wave_n0 + ci * 16 + l15;
        float bias = b_attn[n];
        int d = n & 63;
        int tv = t0 + ri * 16 + quad * 4;
        int it = tv >> 7, ks2 = (tv >> 5) & 3, qd = (tv >> 3) & 3, jj = tv & 7;
        ushort4 pk;
        pk.x = f2bf(acc[ri][ci][0] + bias);
        pk.y = f2bf(acc[ri][ci][1] + bias);
        pk.z = f2bf(acc[ri][ci][2] + bias);
        pk.w = f2bf(acc[ri][ci][3] + bias);
        size_t idx = ((((size_t)bh * 16 + it) * 4 + ks2) * 64 + d) * 32 + qd * 8 + jj;
        *(ushort4*)&v[idx] = pk;
      }
  }
}

// ---------------- flash attention (r1/r3 structure, unchanged) -----------
__global__ __launch_bounds__(256, 4) void flash_attn(const u16* __restrict__ q,
                                                     const u16* __restrict__ k,
                                                     const u16* __restrict__ vt,
                                                     u16* __restrict__ yb) {
  __shared__ u16 K_lds[2][64 * 64];
  __shared__ u16 P_lds[4 * 2 * 16 * 72];  // per-wave 2 x [16 q][64 +pad]

  const int flat = blockIdx.y * 16 + blockIdx.x;
  const int bh = (flat & 7) * 4 + ((flat >> 3) & 3);
  const int qt = flat >> 5;

  const int tid  = threadIdx.x;
  const int lane = tid & 63, w = tid >> 6;
  const int quad = lane >> 4, l15 = lane & 15;
  const int sw0 = ((quad)     ^ (l15 & 7)) * 8;
  const int sw1 = ((quad + 4) ^ (l15 & 7)) * 8;

  const u16* qp = q  + (size_t)bh * 131072;
  const u16* kp = k  + (size_t)bh * 131072;
  const u16* vp = vt + (size_t)bh * 131072;

  bf16x8 qf[2];
#pragma unroll
  for (int ks = 0; ks < 2; ks++)
    qf[ks] = *(const bf16x8*)(qp + (size_t)(qt * 64 + w * 16 + l15) * 64 + ks * 32 + quad * 8);

  f32x4 l_acc = {};
  f32x4 o[4] = {};

  bf16x8 ones;
  {
    short one = (short)0x3F80;
    ones = (bf16x8){one, one, one, one, one, one, one, one};
  }

  u16* Pw = &P_lds[w * 2 * 16 * 72];

#define S_PHASE(KB, PB)                                                        \
  do {                                                                         \
    _Pragma("unroll")                                                          \
    for (int jt = 0; jt < 4; jt++) {                                           \
      bf16x8 kf0 = *(const bf16x8*)&(KB)[(jt * 16 + l15) * 64 + sw0];          \
      bf16x8 kf1 = *(const bf16x8*)&(KB)[(jt * 16 + l15) * 64 + sw1];          \
      f32x4 s = {0.f, 0.f, 0.f, 0.f};                                          \
      s = MFMA16(kf0, qf[0], s);                                               \
      s = MFMA16(kf1, qf[1], s);                                               \
      u32 pb[4];                                                               \
      _Pragma("unroll")                                                        \
      for (int r = 0; r < 4; r++) pb[r] = __float_as_uint(EXP2(s[r]));         \
      uint2 pk;                                                                \
      pk.x = __builtin_amdgcn_perm(pb[1], pb[0], 0x07060302u);                 \
      pk.y = __builtin_amdgcn_perm(pb[3], pb[2], 0x07060302u);                 \
      *(uint2*)&(PB)[l15 * 72 + jt * 16 + quad * 4] = pk;                      \
    }                                                                          \
  } while (0)

#define PV_PHASE(VIT, PB)                                                      \
  do {                                                                         \
    bf16x8 vf[2][4];                                                           \
    _Pragma("unroll")                                                          \
    for (int dt = 0; dt < 4; dt++)                                             \
      vf[0][dt] = *(const bf16x8*)((VIT) + (dt * 16 + l15) * 32 + quad * 8);   \
    _Pragma("unroll")                                                          \
    for (int dt = 0; dt < 4; dt++)                                             \
      vf[1][dt] = *(const bf16x8*)((VIT) + 2048 + (dt * 16 + l15) * 32 + quad * 8); \
    __builtin_amdgcn_s_setprio(1);                                             \
    _Pragma("unroll")                                                          \
    for (int ks = 0; ks < 2; ks++) {                                           \
      bf16x8 pf = *(const bf16x8*)&(PB)[l15 * 72 + ks * 32 + quad * 8];        \
      l_acc = MFMA16(pf, ones, l_acc);                                         \
      _Pragma("unroll")                                                        \
      for (int dt = 0; dt < 4; dt++)                                           \
        o[dt] = MFMA16(pf, vf[ks][dt], o[dt]);                                 \
    }                                                                          \
    __builtin_amdgcn_s_setprio(0);                                             \
  } while (0)

  stage_sw64(kp, K_lds[0], tid);
  stage_sw64(kp + 4096, K_lds[1], tid);
  __syncthreads();
  S_PHASE(K_lds[0], Pw);

  for (int it = 0; it < 31; it++) {
    __syncthreads();
    if (it < 30) stage_sw64(kp + (size_t)(it + 2) * 4096, K_lds[it & 1], tid);
    u16* Pc = Pw + (it & 1) * 16 * 72;
    u16* Pn = Pw + ((it + 1) & 1) * 16 * 72;
    S_PHASE(K_lds[(it + 1) & 1], Pn);
    PV_PHASE(vp + (it) * 4096, Pc);
  }
  PV_PHASE(vp + 31 * 4096, Pw + (31 & 1) * 16 * 72);

#undef S_PHASE
#undef PV_PHASE

  const int b = bh >> 3, h = bh & 7;
  u32* Tw = (u32*)Pw;
#pragma unroll
  for (int r = 0; r < 4; r++) {
    float inv = 1.f / l_acc[r];
#pragma unroll
    for (int dt = 0; dt < 4; dt++) {
      float val = o[dt][r] * inv;
      u16 hi = f2bf(val);
      u16 lo = f2bf(val - bf2f(hi));
      Tw[(quad * 4 + r) * 68 + dt * 16 + l15] = (u32)hi | ((u32)lo << 16);
    }
  }
  {
    int t = qt * 64 + w * 16 + l15;
    size_t rowb = (size_t)(b * 2048 + t) * 512 + h * 64 + quad * 16;
    uint4 g0 = *(uint4*)&Tw[l15 * 68 + quad * 16 + 0];
    uint4 g1 = *(uint4*)&Tw[l15 * 68 + quad * 16 + 4];
    uint4 g2 = *(uint4*)&Tw[l15 * 68 + quad * 16 + 8];
    uint4 g3 = *(uint4*)&Tw[l15 * 68 + quad * 16 + 12];
    uint4 hi4, lo4;
    hi4.x = __builtin_amdgcn_perm(g0.y, g0.x, 0x05040100u);
    hi4.y = __builtin_amdgcn_perm(g0.w, g0.z, 0x05040100u);
    hi4.z = __builtin_amdgcn_perm(g1.y, g1.x, 0x05040100u);
    hi4.w = __builtin_amdgcn_perm(g1.w, g1.z, 0x05040100u);
    lo4.x = __builtin_amdgcn_perm(g0.y, g0.x, 0x07060302u);
    lo4.y = __builtin_amdgcn_perm(g0.w, g0.z, 0x07060302u);
    lo4.z = __builtin_amdgcn_perm(g1.y, g1.x, 0x07060302u);
    lo4.w = __builtin_amdgcn_perm(g1.w, g1.z, 0x07060302u);
    *(uint4*)&yb[rowb] = hi4;
    *(uint4*)&yb[(size_t)4 * 2048 * 512 + rowb] = lo4;
    hi4.x = __builtin_amdgcn_perm(g2.y, g2.x, 0x05040100u);
    hi4.y = __builtin_amdgcn_perm(g2.w, g2.z, 0x05040100u);
    hi4.z = __builtin_amdgcn_perm(g3.y, g3.x, 0x05040100u);
    hi4.w = __builtin_amdgcn_perm(g3.w, g3.z, 0x05040100u);
    lo4.x = __builtin_amdgcn_perm(g2.y, g2.x, 0x07060302u);
    lo4.y = __builtin_amdgcn_perm(g2.w, g2.z, 0x07060302u);
    lo4.z = __builtin_amdgcn_perm(g3.y, g3.x, 0x07060302u);
    lo4.w = __builtin_amdgcn_perm(g3.w, g3.z, 0x07060302u);
    *(uint4*)&yb[rowb + 8] = hi4;
    *(uint4*)&yb[(size_t)4 * 2048 * 512 + rowb + 8] = lo4;
  }
}

// ---------------- output projection (r4 128x64 m97 structure) ------------
// 512 blocks, 48 KB LDS, single-buf stage->sync->compute->sync, 4x2 acc.
__global__ __launch_bounds__(256) void gemm_out(const u16* __restrict__ yhi,
                                                const u16* __restrict__ ylo,
                                                const u16* __restrict__ whi,
                                                const u16* __restrict__ wlo,
                                                const float* __restrict__ b_out,
                                                float* __restrict__ out) {
  __shared__ u16 Ah[128 * 64];
  __shared__ u16 Al[128 * 64];
  __shared__ u16 Bh[64 * 64];
  __shared__ u16 Bl[64 * 64];
  const int bid = blockIdx.x;
  const int xcd = bid & 7, rr = bid >> 3;       // rr in [0,64)
  const int m0 = (xcd * 8 + (rr & 7)) * 128;    // 64 m-tiles
  const int n0 = (rr >> 3) * 64;                // 8 n-tiles
  const int tid  = threadIdx.x;
  const int lane = tid & 63, w = tid >> 6;
  const int wm = w >> 1, wn = w & 1;
  const int quad = lane >> 4, l15 = lane & 15;
  const int sw0 = ((quad)     ^ (l15 & 7)) * 8;
  const int sw1 = ((quad + 4) ^ (l15 & 7)) * 8;

  f32x4 acc[4][2] = {};

  for (int kt = 0; kt < 8; kt++) {
    const int k0 = kt * 64;
    stage_ld512<128>(yhi + (size_t)m0 * 512 + k0, Ah, tid);
    stage_ld512<128>(ylo + (size_t)m0 * 512 + k0, Al, tid);
    stage_ld512<64>(whi + (size_t)n0 * 512 + k0, Bh, tid);
    stage_ld512<64>(wlo + (size_t)n0 * 512 + k0, Bl, tid);
    __syncthreads();
#pragma unroll
    for (int ks = 0; ks < 2; ks++) {
      const int sw = ks ? sw1 : sw0;
      bf16x8 afh[4], afl[4], bfh[2], bfl[2];
#pragma unroll
      for (int ri = 0; ri < 4; ri++) {
        afh[ri] = *(const bf16x8*)&Ah[(wm * 64 + ri * 16 + l15) * 64 + sw];
        afl[ri] = *(const bf16x8*)&Al[(wm * 64 + ri * 16 + l15) * 64 + sw];
      }
#pragma unroll
      for (int ci = 0; ci < 2; ci++) {
        bfh[ci] = *(const bf16x8*)&Bh[(wn * 32 + ci * 16 + l15) * 64 + sw];
        bfl[ci] = *(const bf16x8*)&Bl[(wn * 32 + ci * 16 + l15) * 64 + sw];
      }
#pragma unroll
      for (int ri = 0; ri < 4; ri++)
#pragma unroll
        for (int ci = 0; ci < 2; ci++) {
          acc[ri][ci] = MFMA16(afh[ri], bfh[ci], acc[ri][ci]);
          acc[ri][ci] = MFMA16(afh[ri], bfl[ci], acc[ri][ci]);
          acc[ri][ci] = MFMA16(afl[ri], bfh[ci], acc[ri][ci]);
        }
    }
    __syncthreads();
  }

#pragma unroll
  for (int ri = 0; ri < 4; ri++) {
#pragma unroll
    for (int ci = 0; ci < 2; ci++) {
      int n = n0 + wn * 32 + ci * 16 + l15;
      float bias = b_out[n];
#pragma unroll
      for (int r = 0; r < 4; r++) {
        int m = m0 + wm * 64 + ri * 16 + quad * 4 + r;
        out[(size_t)m * 512 + n] = acc[ri][ci][r] + bias;
      }
    }
  }
}

// ---------------- launch ----------------
extern "C" void kernel_launch(void* const* d_in, const int* in_sizes, int n_in,
                              void* d_out, int out_size, void* d_ws, size_t ws_size,
                              hipStream_t stream) {
  const float* x      = (const float*)d_in[0];
  const float* W_attn = (const float*)d_in[1];
  const float* b_attn = (const float*)d_in[2];
  const float* W_out  = (const float*)d_in[3];
  const float* b_out  = (const float*)d_in[4];
  float* out = (float*)d_out;

  char* ws = (char*)d_ws;
  u16* xb   = (u16*)(ws + 0);                 //  8 MB  [8192][512]
  u16* wta  = (u16*)(ws + 8388608);           //  1.5MB [1536][512]
  u16* wtoh = (u16*)(ws + 9961472);           //  0.5MB [512][512]
  u16* wtol = (u16*)(ws + 10485760);          //  0.5MB
  u16* qb   = (u16*)(ws + 11010048);          //  8 MB  [bh][t][64] (pre-scaled)
  u16* kb   = (u16*)(ws + 19398656);          //  8 MB  [bh][t][64]
  u16* vtb  = (u16*)(ws + 27787264);          //  8 MB  V' frag-packed
  u16* yhi  = (u16*)(ws + 36175872);          //  8 MB  [B,T,C] (+8 MB lo plane)

  prep_kernel<<<4352, 256, 0, stream>>>(x, xb, W_attn, wta, W_out, wtoh, wtol);
  gemm_qkv<<<768, 256, 0, stream>>>(xb, wta, b_attn, qb, kb, vtb);
  flash_attn<<<dim3(16, 64), 256, 0, stream>>>(qb, kb, vtb, yhi);
  gemm_out<<<512, 256, 0, stream>>>(yhi, yhi + (size_t)4 * 2048 * 512, wtoh, wtol, b_out, out);
}

// Round 11
// 175.460 us; speedup vs baseline: 1.7673x; 1.1015x over previous
//
#include <hip/hip_runtime.h>

typedef __attribute__((ext_vector_type(8))) short bf16x8;
typedef __attribute__((ext_vector_type(4))) float f32x4;
typedef unsigned short u16;
typedef unsigned int u32;

#define MFMA16(A, B, C) __builtin_amdgcn_mfma_f32_16x16x32_bf16((A), (B), (C), 0, 0, 0)

#if __has_builtin(__builtin_amdgcn_exp2f)
#define EXP2(x) __builtin_amdgcn_exp2f(x)
#else
#define EXP2(x) exp2f(x)
#endif

typedef __attribute__((address_space(3))) unsigned int lds_u32;
typedef const __attribute__((address_space(1))) unsigned int glb_u32;

__device__ __forceinline__ u16 f2bf(float f) {
  union { float f; unsigned u; } x; x.f = f;
  unsigned r = (x.u + 0x7fffu + ((x.u >> 16) & 1u)) >> 16;
  return (u16)r;
}
__device__ __forceinline__ float bf2f(u16 h) {
  union { float f; unsigned u; } x; x.u = ((unsigned)h) << 16;
  return x.f;
}

// stage a 64x64 bf16 tile (ld=64) into contiguous LDS via global_load_lds,
// XOR-swizzled: LDS slot (row, c) holds global chunk c^(row&7).
__device__ __forceinline__ void stage_sw64(const u16* src, u16* lds, int tid) {
#pragma unroll
  for (int i = 0; i < 2; i++) {
    int vv = tid + i * 256;
    int row = vv >> 3, c = vv & 7;
    const u16* gp = src + (size_t)row * 64 + (size_t)(c ^ (row & 7)) * 8;
    __builtin_amdgcn_global_load_lds((glb_u32*)gp,
        (lds_u32*)(lds + (size_t)(i * 256 + (tid & 192)) * 8), 16, 0, 0);
  }
}

// stage 8KB linearly (V' tile is consumed at its natural layout; the PV read
// pattern distributes evenly across banks without a swizzle).
__device__ __forceinline__ void stage_lin64(const u16* src, u16* lds, int tid) {
#pragma unroll
  for (int i = 0; i < 2; i++) {
    const u16* gp = src + (size_t)(i * 256 + tid) * 8;
    __builtin_amdgcn_global_load_lds((glb_u32*)gp,
        (lds_u32*)(lds + (size_t)(i * 256 + (tid & 192)) * 8), 16, 0, 0);
  }
}

// stage ROWS x 64 bf16 tile from a row-major [*][512] matrix (ld=512) into
// contiguous LDS, same XOR swizzle.
template <int ROWS>
__device__ __forceinline__ void stage_ld512(const u16* src, u16* lds, int tid) {
#pragma unroll
  for (int i = 0; i < ROWS / 32; i++) {
    int vv = tid + i * 256;
    int row = vv >> 3, c = vv & 7;
    const u16* gp = src + (size_t)row * 512 + (size_t)(c ^ (row & 7)) * 8;
    __builtin_amdgcn_global_load_lds((glb_u32*)gp,
        (lds_u32*)(lds + (size_t)(i * 256 + (tid & 192)) * 8), 16, 0, 0);
  }
}

// ---------------- fused prep kernel ----------------
// blocks [0,4096): cast x -> xb (bf16)
// blocks [4096,4288): W_attn -> wta [1536][512] bf16 transposed
// blocks [4288,4352): W_out -> whi/wlo transposed hi/lo
__global__ __launch_bounds__(256) void prep_kernel(const float* __restrict__ x,
                                                   u16* __restrict__ xb,
                                                   const float* __restrict__ Wa,
                                                   u16* __restrict__ wta,
                                                   const float* __restrict__ Wo,
                                                   u16* __restrict__ whi,
                                                   u16* __restrict__ wlo) {
  __shared__ u16 Th[64][72];
  __shared__ u16 Tl[64][72];
  const int bid = blockIdx.x;
  const int tid = threadIdx.x;

  if (bid < 4096) {
    int i = bid * 256 + tid;
    float4 v = ((const float4*)x)[i];
    ushort4 o;
    o.x = f2bf(v.x); o.y = f2bf(v.y); o.z = f2bf(v.z); o.w = f2bf(v.w);
    ((ushort4*)xb)[i] = o;
    return;
  }

  if (bid < 4288) {
    const int t = bid - 4096;
    const int n0 = (t % 24) * 64;
    const int k0 = (t / 24) * 64;
    const int r = tid >> 4, c4 = (tid & 15) * 4;
#pragma unroll
    for (int i = 0; i < 4; i++) {
      int row = r + i * 16;
      float4 v = *(const float4*)&Wa[(size_t)(k0 + row) * 1536 + n0 + c4];
      Th[c4 + 0][row] = f2bf(v.x);
      Th[c4 + 1][row] = f2bf(v.y);
      Th[c4 + 2][row] = f2bf(v.z);
      Th[c4 + 3][row] = f2bf(v.w);
    }
    __syncthreads();
    const int row = tid >> 2, c16 = (tid & 3) * 16;
    *(uint4*)&wta[(size_t)(n0 + row) * 512 + k0 + c16]     = *(uint4*)&Th[row][c16];
    *(uint4*)&wta[(size_t)(n0 + row) * 512 + k0 + c16 + 8] = *(uint4*)&Th[row][c16 + 8];
    return;
  }

  {
    const int t = bid - 4288;
    const int n0 = (t & 7) * 64;
    const int k0 = (t >> 3) * 64;
    const int r = tid >> 4, c4 = (tid & 15) * 4;
#pragma unroll
    for (int i = 0; i < 4; i++) {
      int row = r + i * 16;
      float4 v = *(const float4*)&Wo[(size_t)(k0 + row) * 512 + n0 + c4];
      float vv[4] = {v.x, v.y, v.z, v.w};
#pragma unroll
      for (int jj = 0; jj < 4; jj++) {
        u16 hi = f2bf(vv[jj]);
        Th[c4 + jj][row] = hi;
        Tl[c4 + jj][row] = f2bf(vv[jj] - bf2f(hi));
      }
    }
    __syncthreads();
    const int row = tid >> 2, c16 = (tid & 3) * 16;
    *(uint4*)&whi[(size_t)(n0 + row) * 512 + k0 + c16]     = *(uint4*)&Th[row][c16];
    *(uint4*)&whi[(size_t)(n0 + row) * 512 + k0 + c16 + 8] = *(uint4*)&Th[row][c16 + 8];
    *(uint4*)&wlo[(size_t)(n0 + row) * 512 + k0 + c16]     = *(uint4*)&Tl[row][c16];
    *(uint4*)&wlo[(size_t)(n0 + row) * 512 + k0 + c16 + 8] = *(uint4*)&Tl[row][c16 + 8];
  }
}

// ---------------- QKV GEMM (128x128 single-buf + coalesced epilogue) -----
__global__ __launch_bounds__(256) void gemm_qkv(const u16* __restrict__ xb,
                                                const u16* __restrict__ wta,
                                                const float* __restrict__ b_attn,
                                                u16* __restrict__ q,
                                                u16* __restrict__ kk,
                                                u16* __restrict__ v) {
  __shared__ u16 Smem[18432];  // [0,8192)=A, [8192,16384)=B, rest epilogue pad
  const int bid = blockIdx.x;
  const int xcd = bid & 7, rr = bid >> 3;       // rr in [0,96)
  const int m0 = (xcd * 8 + (rr & 7)) * 128;    // 64 m-tiles
  const int n0 = (rr >> 3) * 128;               // 12 n-tiles
  const int tid  = threadIdx.x;
  const int lane = tid & 63, w = tid >> 6;
  const int wm = w >> 1, wn = w & 1;
  const int quad = lane >> 4, l15 = lane & 15;
  const int sw0 = ((quad)     ^ (l15 & 7)) * 8;
  const int sw1 = ((quad + 4) ^ (l15 & 7)) * 8;

  f32x4 acc[4][4] = {};

  for (int kt = 0; kt < 8; kt++) {
    stage_ld512<128>(xb  + (size_t)m0 * 512 + kt * 64, Smem, tid);
    stage_ld512<128>(wta + (size_t)n0 * 512 + kt * 64, Smem + 8192, tid);
    __syncthreads();
#pragma unroll
    for (int ks = 0; ks < 2; ks++) {
      const int sw = ks ? sw1 : sw0;
      bf16x8 af[4], bf[4];
#pragma unroll
      for (int ri = 0; ri < 4; ri++)
        af[ri] = *(const bf16x8*)&Smem[(wm * 64 + ri * 16 + l15) * 64 + sw];
#pragma unroll
      for (int ci = 0; ci < 4; ci++)
        bf[ci] = *(const bf16x8*)&Smem[8192 + (wn * 64 + ci * 16 + l15) * 64 + sw];
#pragma unroll
      for (int ri = 0; ri < 4; ri++)
#pragma unroll
        for (int ci = 0; ci < 4; ci++)
          acc[ri][ci] = MFMA16(af[ri], bf[ci], acc[ri][ci]);
    }
    __syncthreads();
  }

  const float QS = 0.18033688011112043f;  // 0.125 * log2(e)
  const int wave_n0 = n0 + wn * 64;
  const int chunk = wave_n0 >> 9;
  const int h = (wave_n0 & 511) >> 6;
  const int m_wave = m0 + wm * 64;
  const int b = m_wave >> 11, t0 = m_wave & 2047;
  const int bh = b * 8 + h;

  if (chunk < 2) {
    // q/k: per-wave LDS transpose -> fully coalesced 128B-row stores
    u16* T = Smem + w * 4608;  // 64 x 72 per-wave scratch (post-barrier reuse)
    u16* dst = (chunk == 0) ? q : kk;
    const float scale = (chunk == 0) ? QS : 1.0f;
#pragma unroll
    for (int ri = 0; ri < 4; ri++)
#pragma unroll
      for (int ci = 0; ci < 4; ci++) {
        float bias = b_attn[wave_n0 + ci * 16 + l15];
#pragma unroll
        for (int r = 0; r < 4; r++) {
          int tl = ri * 16 + quad * 4 + r;
          T[tl * 72 + ci * 16 + l15] = f2bf((acc[ri][ci][r] + bias) * scale);
        }
      }
    u16* gdst = dst + (size_t)(bh * 2048 + t0 + lane) * 64;
#pragma unroll
    for (int j = 0; j < 8; j++)
      *(uint4*)&gdst[j * 8] = *(const uint4*)&T[lane * 72 + j * 8];
  } else {
    // V': frag-packed layout
#pragma unroll
    for (int ri = 0; ri < 4; ri++)
#pragma unroll
      for (int ci = 0; ci < 4; ci++) {
        int n = wave_n0 + ci * 16 + l15;
        float bias = b_attn[n];
        int d = n & 63;
        int tv = t0 + ri * 16 + quad * 4;
        int it = tv >> 7, ks2 = (tv >> 5) & 3, qd = (tv >> 3) & 3, jj = tv & 7;
        ushort4 pk;
        pk.x = f2bf(acc[ri][ci][0] + bias);
        pk.y = f2bf(acc[ri][ci][1] + bias);
        pk.z = f2bf(acc[ri][ci][2] + bias);
        pk.w = f2bf(acc[ri][ci][3] + bias);
        size_t idx = ((((size_t)bh * 16 + it) * 4 + ks2) * 64 + d) * 32 + qd * 8 + jj;
        *(ushort4*)&v[idx] = pk;
      }
  }
}

// ---------------- flash attention ----------------
// r11: V' staged into LDS via 1-ahead global_load_lds dbuf (alongside K).
// Mechanism: all 4 waves of a block read the IDENTICAL 8KB V' tile each
// iteration -> 4x redundant L2 loads + one exposed ~200cy vmcnt chain per
// wave per iteration. DMA stages it once; PV reads LDS (prefetched).
// To keep 4 blocks/CU at 40KB exactly: P is single-buffered (r3 measured
// the S/PV pipeline at +-0) at stride 64 with 16B-chunk XOR swizzle
// (chunk ^= l15&7; write 2-way / read 2-way = conflict-free). Epilogue
// transpose scratch reuses the K region after a barrier.
__global__ __launch_bounds__(256, 4) void flash_attn(const u16* __restrict__ q,
                                                     const u16* __restrict__ k,
                                                     const u16* __restrict__ vt,
                                                     u16* __restrict__ yb) {
  __shared__ u16 Kb[2][64 * 64];   // 16 KB
  __shared__ u16 Vb[2][64 * 64];   // 16 KB
  __shared__ u16 P_lds[4 * 16 * 64];  // 8 KB (per-wave [16 q][64 k], swizzled)
  // total = 40960 B exactly -> 4 blocks/CU

  const int flat = blockIdx.y * 16 + blockIdx.x;
  const int bh = (flat & 7) * 4 + ((flat >> 3) & 3);
  const int qt = flat >> 5;

  const int tid  = threadIdx.x;
  const int lane = tid & 63, w = tid >> 6;
  const int quad = lane >> 4, l15 = lane & 15;
  const int sw0 = ((quad)     ^ (l15 & 7)) * 8;
  const int sw1 = ((quad + 4) ^ (l15 & 7)) * 8;

  const u16* qp = q  + (size_t)bh * 131072;
  const u16* kp = k  + (size_t)bh * 131072;
  const u16* vp = vt + (size_t)bh * 131072;

  bf16x8 qf[2];
#pragma unroll
  for (int ks = 0; ks < 2; ks++)
    qf[ks] = *(const bf16x8*)(qp + (size_t)(qt * 64 + w * 16 + l15) * 64 + ks * 32 + quad * 8);

  f32x4 l_acc = {};
  f32x4 o[4] = {};

  bf16x8 ones;
  {
    short one = (short)0x3F80;
    ones = (bf16x8){one, one, one, one, one, one, one, one};
  }

  u16* Pw = &P_lds[w * 1024];
  const int psw = l15 & 7;

  stage_sw64(kp, Kb[0], tid);
  stage_lin64(vp, Vb[0], tid);

  for (int it = 0; it < 32; it++) {
    __syncthreads();   // K[it],V[it] landed; prior reads of overwritten bufs done
    if (it < 31) {
      stage_sw64(kp + (size_t)(it + 1) * 4096, Kb[(it + 1) & 1], tid);
      stage_lin64(vp + (size_t)(it + 1) * 4096, Vb[(it + 1) & 1], tid);
    }
    const u16* Kc = Kb[it & 1];
    const u16* Vc = Vb[it & 1];

    // S phase: MFMA -> exp2 -> pack -> per-wave swizzled P
#pragma unroll
    for (int jt = 0; jt < 4; jt++) {
      bf16x8 kf0 = *(const bf16x8*)&Kc[(jt * 16 + l15) * 64 + sw0];
      bf16x8 kf1 = *(const bf16x8*)&Kc[(jt * 16 + l15) * 64 + sw1];
      f32x4 s = {0.f, 0.f, 0.f, 0.f};
      s = MFMA16(kf0, qf[0], s);
      s = MFMA16(kf1, qf[1], s);
      u32 pb[4];
#pragma unroll
      for (int r = 0; r < 4; r++) pb[r] = __float_as_uint(EXP2(s[r]));
      uint2 pk;
      pk.x = __builtin_amdgcn_perm(pb[1], pb[0], 0x07060302u);
      pk.y = __builtin_amdgcn_perm(pb[3], pb[2], 0x07060302u);
      int c = jt * 2 + (quad >> 1);
      *(uint2*)&Pw[l15 * 64 + ((c ^ psw) << 3) + (quad & 1) * 4] = pk;
    }

    // PV phase: P + V both from LDS (same-wave RAW via lgkmcnt)
    __builtin_amdgcn_s_setprio(1);
#pragma unroll
    for (int ks = 0; ks < 2; ks++) {
      bf16x8 pf = *(const bf16x8*)&Pw[l15 * 64 + (((ks * 4 + quad) ^ psw) << 3)];
      l_acc = MFMA16(pf, ones, l_acc);
#pragma unroll
      for (int dt = 0; dt < 4; dt++) {
        bf16x8 vf = *(const bf16x8*)&Vc[ks * 2048 + (dt * 16 + l15) * 32 + quad * 8];
        o[dt] = MFMA16(pf, vf, o[dt]);
      }
    }
    __builtin_amdgcn_s_setprio(0);
  }

  __syncthreads();  // all waves done with Kb/Vb; safe to reuse K region

  // epilogue: normalize, transpose via LDS (K region scratch), write hi/lo
  const int b = bh >> 3, h = bh & 7;
  u32* Tw = (u32*)(&Kb[0][0]) + (size_t)w * 1088;  // 16 x 68 u32 per wave
#pragma unroll
  for (int r = 0; r < 4; r++) {
    float inv = 1.f / l_acc[r];
#pragma unroll
    for (int dt = 0; dt < 4; dt++) {
      float val = o[dt][r] * inv;
      u16 hi = f2bf(val);
      u16 lo = f2bf(val - bf2f(hi));
      Tw[(quad * 4 + r) * 68 + dt * 16 + l15] = (u32)hi | ((u32)lo << 16);
    }
  }
  {
    int t = qt * 64 + w * 16 + l15;
    size_t rowb = (size_t)(b * 2048 + t) * 512 + h * 64 + quad * 16;
    uint4 g0 = *(uint4*)&Tw[l15 * 68 + quad * 16 + 0];
    uint4 g1 = *(uint4*)&Tw[l15 * 68 + quad * 16 + 4];
    uint4 g2 = *(uint4*)&Tw[l15 * 68 + quad * 16 + 8];
    uint4 g3 = *(uint4*)&Tw[l15 * 68 + quad * 16 + 12];
    uint4 hi4, lo4;
    hi4.x = __builtin_amdgcn_perm(g0.y, g0.x, 0x05040100u);
    hi4.y = __builtin_amdgcn_perm(g0.w, g0.z, 0x05040100u);
    hi4.z = __builtin_amdgcn_perm(g1.y, g1.x, 0x05040100u);
    hi4.w = __builtin_amdgcn_perm(g1.w, g1.z, 0x05040100u);
    lo4.x = __builtin_amdgcn_perm(g0.y, g0.x, 0x07060302u);
    lo4.y = __builtin_amdgcn_perm(g0.w, g0.z, 0x07060302u);
    lo4.z = __builtin_amdgcn_perm(g1.y, g1.x, 0x07060302u);
    lo4.w = __builtin_amdgcn_perm(g1.w, g1.z, 0x07060302u);
    *(uint4*)&yb[rowb] = hi4;
    *(uint4*)&yb[(size_t)4 * 2048 * 512 + rowb] = lo4;
    hi4.x = __builtin_amdgcn_perm(g2.y, g2.x, 0x05040100u);
    hi4.y = __builtin_amdgcn_perm(g2.w, g2.z, 0x05040100u);
    hi4.z = __builtin_amdgcn_perm(g3.y, g3.x, 0x05040100u);
    hi4.w = __builtin_amdgcn_perm(g3.w, g3.z, 0x05040100u);
    lo4.x = __builtin_amdgcn_perm(g2.y, g2.x, 0x07060302u);
    lo4.y = __builtin_amdgcn_perm(g2.w, g2.z, 0x07060302u);
    lo4.z = __builtin_amdgcn_perm(g3.y, g3.x, 0x07060302u);
    lo4.w = __builtin_amdgcn_perm(g3.w, g3.z, 0x07060302u);
    *(uint4*)&yb[rowb + 8] = hi4;
    *(uint4*)&yb[(size_t)4 * 2048 * 512 + rowb + 8] = lo4;
  }
}

// ---------------- output projection (128x64 m97 structure) ---------------
__global__ __launch_bounds__(256) void gemm_out(const u16* __restrict__ yhi,
                                                const u16* __restrict__ ylo,
                                                const u16* __restrict__ whi,
                                                const u16* __restrict__ wlo,
                                                const float* __restrict__ b_out,
                                                float* __restrict__ out) {
  __shared__ u16 Ah[128 * 64];
  __shared__ u16 Al[128 * 64];
  __shared__ u16 Bh[64 * 64];
  __shared__ u16 Bl[64 * 64];
  const int bid = blockIdx.x;
  const int xcd = bid & 7, rr = bid >> 3;       // rr in [0,64)
  const int m0 = (xcd * 8 + (rr & 7)) * 128;    // 64 m-tiles
  const int n0 = (rr >> 3) * 64;                // 8 n-tiles
  const int tid  = threadIdx.x;
  const int lane = tid & 63, w = tid >> 6;
  const int wm = w >> 1, wn = w & 1;
  const int quad = lane >> 4, l15 = lane & 15;
  const int sw0 = ((quad)     ^ (l15 & 7)) * 8;
  const int sw1 = ((quad + 4) ^ (l15 & 7)) * 8;

  f32x4 acc[4][2] = {};

  for (int kt = 0; kt < 8; kt++) {
    const int k0 = kt * 64;
    stage_ld512<128>(yhi + (size_t)m0 * 512 + k0, Ah, tid);
    stage_ld512<128>(ylo + (size_t)m0 * 512 + k0, Al, tid);
    stage_ld512<64>(whi + (size_t)n0 * 512 + k0, Bh, tid);
    stage_ld512<64>(wlo + (size_t)n0 * 512 + k0, Bl, tid);
    __syncthreads();
#pragma unroll
    for (int ks = 0; ks < 2; ks++) {
      const int sw = ks ? sw1 : sw0;
      bf16x8 afh[4], afl[4], bfh[2], bfl[2];
#pragma unroll
      for (int ri = 0; ri < 4; ri++) {
        afh[ri] = *(const bf16x8*)&Ah[(wm * 64 + ri * 16 + l15) * 64 + sw];
        afl[ri] = *(const bf16x8*)&Al[(wm * 64 + ri * 16 + l15) * 64 + sw];
      }
#pragma unroll
      for (int ci = 0; ci < 2; ci++) {
        bfh[ci] = *(const bf16x8*)&Bh[(wn * 32 + ci * 16 + l15) * 64 + sw];
        bfl[ci] = *(const bf16x8*)&Bl[(wn * 32 + ci * 16 + l15) * 64 + sw];
      }
#pragma unroll
      for (int ri = 0; ri < 4; ri++)
#pragma unroll
        for (int ci = 0; ci < 2; ci++) {
          acc[ri][ci] = MFMA16(afh[ri], bfh[ci], acc[ri][ci]);
          acc[ri][ci] = MFMA16(afh[ri], bfl[ci], acc[ri][ci]);
          acc[ri][ci] = MFMA16(afl[ri], bfh[ci], acc[ri][ci]);
        }
    }
    __syncthreads();
  }

#pragma unroll
  for (int ri = 0; ri < 4; ri++) {
#pragma unroll
    for (int ci = 0; ci < 2; ci++) {
      int n = n0 + wn * 32 + ci * 16 + l15;
      float bias = b_out[n];
#pragma unroll
      for (int r = 0; r < 4; r++) {
        int m = m0 + wm * 64 + ri * 16 + quad * 4 + r;
        out[(size_t)m * 512 + n] = acc[ri][ci][r] + bias;
      }
    }
  }
}

// ---------------- launch ----------------
extern "C" void kernel_launch(void* const* d_in, const int* in_sizes, int n_in,
                              void* d_out, int out_size, void* d_ws, size_t ws_size,
                              hipStream_t stream) {
  const float* x      = (const float*)d_in[0];
  const float* W_attn = (const float*)d_in[1];
  const float* b_attn = (const float*)d_in[2];
  const float* W_out  = (const float*)d_in[3];
  const float* b_out  = (const float*)d_in[4];
  float* out = (float*)d_out;

  char* ws = (char*)d_ws;
  u16* xb   = (u16*)(ws + 0);                 //  8 MB  [8192][512]
  u16* wta  = (u16*)(ws + 8388608);           //  1.5MB [1536][512]
  u16* wtoh = (u16*)(ws + 9961472);           //  0.5MB [512][512]
  u16* wtol = (u16*)(ws + 10485760);          //  0.5MB
  u16* qb   = (u16*)(ws + 11010048);          //  8 MB  [bh][t][64] (pre-scaled)
  u16* kb   = (u16*)(ws + 19398656);          //  8 MB  [bh][t][64]
  u16* vtb  = (u16*)(ws + 27787264);          //  8 MB  V' frag-packed
  u16* yhi  = (u16*)(ws + 36175872);          //  8 MB  [B,T,C] (+8 MB lo plane)

  prep_kernel<<<4352, 256, 0, stream>>>(x, xb, W_attn, wta, W_out, wtoh, wtol);
  gemm_qkv<<<768, 256, 0, stream>>>(xb, wta, b_attn, qb, kb, vtb);
  flash_attn<<<dim3(16, 64), 256, 0, stream>>>(qb, kb, vtb, yhi);
  gemm_out<<<512, 256, 0, stream>>>(yhi, yhi + (size_t)4 * 2048 * 512, wtoh, wtol, b_out, out);
}

// Round 12
// 175.034 us; speedup vs baseline: 1.7716x; 1.0024x over previous
//
#include <hip/hip_runtime.h>

typedef __attribute__((ext_vector_type(8))) short bf16x8;
typedef __attribute__((ext_vector_type(4))) float f32x4;
typedef unsigned short u16;
typedef unsigned int u32;

#define MFMA16(A, B, C) __builtin_amdgcn_mfma_f32_16x16x32_bf16((A), (B), (C), 0, 0, 0)

#if __has_builtin(__builtin_amdgcn_exp2f)
#define EXP2(x) __builtin_amdgcn_exp2f(x)
#else
#define EXP2(x) exp2f(x)
#endif

typedef __attribute__((address_space(3))) unsigned int lds_u32;
typedef const __attribute__((address_space(1))) unsigned int glb_u32;

__device__ __forceinline__ u16 f2bf(float f) {
  union { float f; unsigned u; } x; x.f = f;
  unsigned r = (x.u + 0x7fffu + ((x.u >> 16) & 1u)) >> 16;
  return (u16)r;
}
__device__ __forceinline__ float bf2f(u16 h) {
  union { float f; unsigned u; } x; x.u = ((unsigned)h) << 16;
  return x.f;
}

// 256-thread stagers (GEMM kernels) -----------------------------------
__device__ __forceinline__ void stage_sw64(const u16* src, u16* lds, int tid) {
#pragma unroll
  for (int i = 0; i < 2; i++) {
    int vv = tid + i * 256;
    int row = vv >> 3, c = vv & 7;
    const u16* gp = src + (size_t)row * 64 + (size_t)(c ^ (row & 7)) * 8;
    __builtin_amdgcn_global_load_lds((glb_u32*)gp,
        (lds_u32*)(lds + (size_t)(i * 256 + (tid & 192)) * 8), 16, 0, 0);
  }
}

template <int ROWS>
__device__ __forceinline__ void stage_ld512(const u16* src, u16* lds, int tid) {
#pragma unroll
  for (int i = 0; i < ROWS / 32; i++) {
    int vv = tid + i * 256;
    int row = vv >> 3, c = vv & 7;
    const u16* gp = src + (size_t)row * 512 + (size_t)(c ^ (row & 7)) * 8;
    __builtin_amdgcn_global_load_lds((glb_u32*)gp,
        (lds_u32*)(lds + (size_t)(i * 256 + (tid & 192)) * 8), 16, 0, 0);
  }
}

// 128-thread stagers (flash) ------------------------------------------
__device__ __forceinline__ void stage_sw64_128(const u16* src, u16* lds, int tid) {
#pragma unroll
  for (int i = 0; i < 4; i++) {
    int vv = tid + i * 128;
    int row = vv >> 3, c = vv & 7;
    const u16* gp = src + (size_t)row * 64 + (size_t)(c ^ (row & 7)) * 8;
    __builtin_amdgcn_global_load_lds((glb_u32*)gp,
        (lds_u32*)(lds + (size_t)(i * 128 + (tid & 64)) * 8), 16, 0, 0);
  }
}
__device__ __forceinline__ void stage_lin64_128(const u16* src, u16* lds, int tid) {
#pragma unroll
  for (int i = 0; i < 4; i++) {
    const u16* gp = src + (size_t)(i * 128 + tid) * 8;
    __builtin_amdgcn_global_load_lds((glb_u32*)gp,
        (lds_u32*)(lds + (size_t)(i * 128 + (tid & 64)) * 8), 16, 0, 0);
  }
}

// ---------------- fused prep kernel ----------------
__global__ __launch_bounds__(256) void prep_kernel(const float* __restrict__ x,
                                                   u16* __restrict__ xb,
                                                   const float* __restrict__ Wa,
                                                   u16* __restrict__ wta,
                                                   const float* __restrict__ Wo,
                                                   u16* __restrict__ whi,
                                                   u16* __restrict__ wlo) {
  __shared__ u16 Th[64][72];
  __shared__ u16 Tl[64][72];
  const int bid = blockIdx.x;
  const int tid = threadIdx.x;

  if (bid < 4096) {
    int i = bid * 256 + tid;
    float4 v = ((const float4*)x)[i];
    ushort4 o;
    o.x = f2bf(v.x); o.y = f2bf(v.y); o.z = f2bf(v.z); o.w = f2bf(v.w);
    ((ushort4*)xb)[i] = o;
    return;
  }

  if (bid < 4288) {
    const int t = bid - 4096;
    const int n0 = (t % 24) * 64;
    const int k0 = (t / 24) * 64;
    const int r = tid >> 4, c4 = (tid & 15) * 4;
#pragma unroll
    for (int i = 0; i < 4; i++) {
      int row = r + i * 16;
      float4 v = *(const float4*)&Wa[(size_t)(k0 + row) * 1536 + n0 + c4];
      Th[c4 + 0][row] = f2bf(v.x);
      Th[c4 + 1][row] = f2bf(v.y);
      Th[c4 + 2][row] = f2bf(v.z);
      Th[c4 + 3][row] = f2bf(v.w);
    }
    __syncthreads();
    const int row = tid >> 2, c16 = (tid & 3) * 16;
    *(uint4*)&wta[(size_t)(n0 + row) * 512 + k0 + c16]     = *(uint4*)&Th[row][c16];
    *(uint4*)&wta[(size_t)(n0 + row) * 512 + k0 + c16 + 8] = *(uint4*)&Th[row][c16 + 8];
    return;
  }

  {
    const int t = bid - 4288;
    const int n0 = (t & 7) * 64;
    const int k0 = (t >> 3) * 64;
    const int r = tid >> 4, c4 = (tid & 15) * 4;
#pragma unroll
    for (int i = 0; i < 4; i++) {
      int row = r + i * 16;
      float4 v = *(const float4*)&Wo[(size_t)(k0 + row) * 512 + n0 + c4];
      float vv[4] = {v.x, v.y, v.z, v.w};
#pragma unroll
      for (int jj = 0; jj < 4; jj++) {
        u16 hi = f2bf(vv[jj]);
        Th[c4 + jj][row] = hi;
        Tl[c4 + jj][row] = f2bf(vv[jj] - bf2f(hi));
      }
    }
    __syncthreads();
    const int row = tid >> 2, c16 = (tid & 3) * 16;
    *(uint4*)&whi[(size_t)(n0 + row) * 512 + k0 + c16]     = *(uint4*)&Th[row][c16];
    *(uint4*)&whi[(size_t)(n0 + row) * 512 + k0 + c16 + 8] = *(uint4*)&Th[row][c16 + 8];
    *(uint4*)&wlo[(size_t)(n0 + row) * 512 + k0 + c16]     = *(uint4*)&Tl[row][c16];
    *(uint4*)&wlo[(size_t)(n0 + row) * 512 + k0 + c16 + 8] = *(uint4*)&Tl[row][c16 + 8];
  }
}

// ---------------- QKV GEMM (128x128 single-buf + coalesced epilogue) -----
__global__ __launch_bounds__(256) void gemm_qkv(const u16* __restrict__ xb,
                                                const u16* __restrict__ wta,
                                                const float* __restrict__ b_attn,
                                                u16* __restrict__ q,
                                                u16* __restrict__ kk,
                                                u16* __restrict__ v) {
  __shared__ u16 Smem[18432];  // [0,8192)=A, [8192,16384)=B, rest epilogue pad
  const int bid = blockIdx.x;
  const int xcd = bid & 7, rr = bid >> 3;       // rr in [0,96)
  const int m0 = (xcd * 8 + (rr & 7)) * 128;    // 64 m-tiles
  const int n0 = (rr >> 3) * 128;               // 12 n-tiles
  const int tid  = threadIdx.x;
  const int lane = tid & 63, w = tid >> 6;
  const int wm = w >> 1, wn = w & 1;
  const int quad = lane >> 4, l15 = lane & 15;
  const int sw0 = ((quad)     ^ (l15 & 7)) * 8;
  const int sw1 = ((quad + 4) ^ (l15 & 7)) * 8;

  f32x4 acc[4][4] = {};

  for (int kt = 0; kt < 8; kt++) {
    stage_ld512<128>(xb  + (size_t)m0 * 512 + kt * 64, Smem, tid);
    stage_ld512<128>(wta + (size_t)n0 * 512 + kt * 64, Smem + 8192, tid);
    __syncthreads();
#pragma unroll
    for (int ks = 0; ks < 2; ks++) {
      const int sw = ks ? sw1 : sw0;
      bf16x8 af[4], bf[4];
#pragma unroll
      for (int ri = 0; ri < 4; ri++)
        af[ri] = *(const bf16x8*)&Smem[(wm * 64 + ri * 16 + l15) * 64 + sw];
#pragma unroll
      for (int ci = 0; ci < 4; ci++)
        bf[ci] = *(const bf16x8*)&Smem[8192 + (wn * 64 + ci * 16 + l15) * 64 + sw];
#pragma unroll
      for (int ri = 0; ri < 4; ri++)
#pragma unroll
        for (int ci = 0; ci < 4; ci++)
          acc[ri][ci] = MFMA16(af[ri], bf[ci], acc[ri][ci]);
    }
    __syncthreads();
  }

  const float QS = 0.18033688011112043f;  // 0.125 * log2(e)
  const int wave_n0 = n0 + wn * 64;
  const int chunk = wave_n0 >> 9;
  const int h = (wave_n0 & 511) >> 6;
  const int m_wave = m0 + wm * 64;
  const int b = m_wave >> 11, t0 = m_wave & 2047;
  const int bh = b * 8 + h;

  if (chunk < 2) {
    u16* T = Smem + w * 4608;  // 64 x 72 per-wave scratch (post-barrier reuse)
    u16* dst = (chunk == 0) ? q : kk;
    const float scale = (chunk == 0) ? QS : 1.0f;
#pragma unroll
    for (int ri = 0; ri < 4; ri++)
#pragma unroll
      for (int ci = 0; ci < 4; ci++) {
        float bias = b_attn[wave_n0 + ci * 16 + l15];
#pragma unroll
        for (int r = 0; r < 4; r++) {
          int tl = ri * 16 + quad * 4 + r;
          T[tl * 72 + ci * 16 + l15] = f2bf((acc[ri][ci][r] + bias) * scale);
        }
      }
    u16* gdst = dst + (size_t)(bh * 2048 + t0 + lane) * 64;
#pragma unroll
    for (int j = 0; j < 8; j++)
      *(uint4*)&gdst[j * 8] = *(const uint4*)&T[lane * 72 + j * 8];
  } else {
#pragma unroll
    for (int ri = 0; ri < 4; ri++)
#pragma unroll
      for (int ci = 0; ci < 4; ci++) {
        int n = wave_n0 + ci * 16 + l15;
        float bias = b_attn[n];
        int d = n & 63;
        int tv = t0 + ri * 16 + quad * 4;
        int it = tv >> 7, ks2 = (tv >> 5) & 3, qd = (tv >> 3) & 3, jj = tv & 7;
        ushort4 pk;
        pk.x = f2bf(acc[ri][ci][0] + bias);
        pk.y = f2bf(acc[ri][ci][1] + bias);
        pk.z = f2bf(acc[ri][ci][2] + bias);
        pk.w = f2bf(acc[ri][ci][3] + bias);
        size_t idx = ((((size_t)bh * 16 + it) * 4 + ks2) * 64 + d) * 32 + qd * 8 + jj;
        *(ushort4*)&v[idx] = pk;
      }
  }
}

// ---------------- flash attention ----------------
// r12: LDS-BW amortization. r11 counters put flash at ~95% of achievable
// LDS BW (12.3 MB/CU over 152K cyc = 81 B/cyc vs 85 b128-rate). Every wave
// reads the FULL K and V tiles per iteration, so traffic/work is set by
// q-rows-per-wave. Now: 128-thread blocks, 2 waves, 32 q-rows/wave (qh=2).
// Each K fragment feeds 2 S-MFMAs; each V fragment feeds 2 PV-MFMAs.
// Per-CU traffic 12.3 -> 8.2 MB (0.67x). 1024 blocks, 40KB -> 4 blocks/CU
// (8 waves in 4 INDEPENDENT blocks).
__global__ __launch_bounds__(128, 2) void flash_attn(const u16* __restrict__ q,
                                                     const u16* __restrict__ k,
                                                     const u16* __restrict__ vt,
                                                     u16* __restrict__ yb) {
  __shared__ u16 Kb[2][64 * 64];      // 16 KB
  __shared__ u16 Vb[2][64 * 64];      // 16 KB
  __shared__ u16 P_lds[2 * 2 * 1024]; // 8 KB: 2 waves x 2 qh x [16q][64k] swizzled
  // total = 40960 B -> 4 blocks/CU

  const int flat = blockIdx.y * 16 + blockIdx.x;
  const int bh = (flat & 7) * 4 + ((flat >> 3) & 3);
  const int qt = flat >> 5;

  const int tid  = threadIdx.x;        // 0..127
  const int lane = tid & 63, w = tid >> 6;  // w in {0,1}
  const int quad = lane >> 4, l15 = lane & 15;
  const int sw0 = ((quad)     ^ (l15 & 7)) * 8;
  const int sw1 = ((quad + 4) ^ (l15 & 7)) * 8;

  const u16* qp = q  + (size_t)bh * 131072;
  const u16* kp = k  + (size_t)bh * 131072;
  const u16* vp = vt + (size_t)bh * 131072;

  // wave owns 32 q-rows: qt*64 + w*32 + qh*16 + l15
  bf16x8 qf[2][2];
#pragma unroll
  for (int qh = 0; qh < 2; qh++)
#pragma unroll
    for (int ks = 0; ks < 2; ks++)
      qf[qh][ks] = *(const bf16x8*)(qp + (size_t)(qt * 64 + w * 32 + qh * 16 + l15) * 64 + ks * 32 + quad * 8);

  f32x4 l_acc[2] = {};
  f32x4 o[2][4] = {};

  bf16x8 ones;
  {
    short one = (short)0x3F80;
    ones = (bf16x8){one, one, one, one, one, one, one, one};
  }

  u16* Pw = &P_lds[w * 2048];      // 2 qh x 1024 u16
  const int psw = l15 & 7;

  stage_sw64_128(kp, Kb[0], tid);
  stage_lin64_128(vp, Vb[0], tid);

  for (int it = 0; it < 32; it++) {
    __syncthreads();   // K[it],V[it] landed; prior reads of overwritten bufs done
    if (it < 31) {
      stage_sw64_128(kp + (size_t)(it + 1) * 4096, Kb[(it + 1) & 1], tid);
      stage_lin64_128(vp + (size_t)(it + 1) * 4096, Vb[(it + 1) & 1], tid);
    }
    const u16* Kc = Kb[it & 1];
    const u16* Vc = Vb[it & 1];

    // S phase: each K fragment read once, used by BOTH q-halves
#pragma unroll
    for (int jt = 0; jt < 4; jt++) {
      bf16x8 kf0 = *(const bf16x8*)&Kc[(jt * 16 + l15) * 64 + sw0];
      bf16x8 kf1 = *(const bf16x8*)&Kc[(jt * 16 + l15) * 64 + sw1];
      const int c = jt * 2 + (quad >> 1);
#pragma unroll
      for (int qh = 0; qh < 2; qh++) {
        f32x4 s = {0.f, 0.f, 0.f, 0.f};
        s = MFMA16(kf0, qf[qh][0], s);
        s = MFMA16(kf1, qf[qh][1], s);
        u32 pb[4];
#pragma unroll
        for (int r = 0; r < 4; r++) pb[r] = __float_as_uint(EXP2(s[r]));
        uint2 pk;
        pk.x = __builtin_amdgcn_perm(pb[1], pb[0], 0x07060302u);
        pk.y = __builtin_amdgcn_perm(pb[3], pb[2], 0x07060302u);
        *(uint2*)&Pw[qh * 1024 + l15 * 64 + ((c ^ psw) << 3) + (quad & 1) * 4] = pk;
      }
    }

    // PV phase: each V fragment read once, used by BOTH q-halves
    __builtin_amdgcn_s_setprio(1);
#pragma unroll
    for (int ks = 0; ks < 2; ks++) {
      bf16x8 pf0 = *(const bf16x8*)&Pw[       l15 * 64 + (((ks * 4 + quad) ^ psw) << 3)];
      bf16x8 pf1 = *(const bf16x8*)&Pw[1024 + l15 * 64 + (((ks * 4 + quad) ^ psw) << 3)];
      l_acc[0] = MFMA16(pf0, ones, l_acc[0]);
      l_acc[1] = MFMA16(pf1, ones, l_acc[1]);
#pragma unroll
      for (int dt = 0; dt < 4; dt++) {
        bf16x8 vf = *(const bf16x8*)&Vc[ks * 2048 + (dt * 16 + l15) * 32 + quad * 8];
        o[0][dt] = MFMA16(pf0, vf, o[0][dt]);
        o[1][dt] = MFMA16(pf1, vf, o[1][dt]);
      }
    }
    __builtin_amdgcn_s_setprio(0);
  }

  __syncthreads();  // all waves done with Kb/Vb; safe to reuse K region

  // epilogue per q-half: normalize, LDS transpose (K-region scratch), store
  const int b = bh >> 3, h = bh & 7;
  u32* Tw = (u32*)(&Kb[0][0]) + (size_t)w * 1088;  // 16 x 68 u32 per wave
#pragma unroll
  for (int qh = 0; qh < 2; qh++) {
#pragma unroll
    for (int r = 0; r < 4; r++) {
      float inv = 1.f / l_acc[qh][r];
#pragma unroll
      for (int dt = 0; dt < 4; dt++) {
        float val = o[qh][dt][r] * inv;
        u16 hi = f2bf(val);
        u16 lo = f2bf(val - bf2f(hi));
        Tw[(quad * 4 + r) * 68 + dt * 16 + l15] = (u32)hi | ((u32)lo << 16);
      }
    }
    int t = qt * 64 + w * 32 + qh * 16 + l15;
    size_t rowb = (size_t)(b * 2048 + t) * 512 + h * 64 + quad * 16;
    uint4 g0 = *(uint4*)&Tw[l15 * 68 + quad * 16 + 0];
    uint4 g1 = *(uint4*)&Tw[l15 * 68 + quad * 16 + 4];
    uint4 g2 = *(uint4*)&Tw[l15 * 68 + quad * 16 + 8];
    uint4 g3 = *(uint4*)&Tw[l15 * 68 + quad * 16 + 12];
    uint4 hi4, lo4;
    hi4.x = __builtin_amdgcn_perm(g0.y, g0.x, 0x05040100u);
    hi4.y = __builtin_amdgcn_perm(g0.w, g0.z, 0x05040100u);
    hi4.z = __builtin_amdgcn_perm(g1.y, g1.x, 0x05040100u);
    hi4.w = __builtin_amdgcn_perm(g1.w, g1.z, 0x05040100u);
    lo4.x = __builtin_amdgcn_perm(g0.y, g0.x, 0x07060302u);
    lo4.y = __builtin_amdgcn_perm(g0.w, g0.z, 0x07060302u);
    lo4.z = __builtin_amdgcn_perm(g1.y, g1.x, 0x07060302u);
    lo4.w = __builtin_amdgcn_perm(g1.w, g1.z, 0x07060302u);
    *(uint4*)&yb[rowb] = hi4;
    *(uint4*)&yb[(size_t)4 * 2048 * 512 + rowb] = lo4;
    hi4.x = __builtin_amdgcn_perm(g2.y, g2.x, 0x05040100u);
    hi4.y = __builtin_amdgcn_perm(g2.w, g2.z, 0x05040100u);
    hi4.z = __builtin_amdgcn_perm(g3.y, g3.x, 0x05040100u);
    hi4.w = __builtin_amdgcn_perm(g3.w, g3.z, 0x05040100u);
    lo4.x = __builtin_amdgcn_perm(g2.y, g2.x, 0x07060302u);
    lo4.y = __builtin_amdgcn_perm(g2.w, g2.z, 0x07060302u);
    lo4.z = __builtin_amdgcn_perm(g3.y, g3.x, 0x07060302u);
    lo4.w = __builtin_amdgcn_perm(g3.w, g3.z, 0x07060302u);
    *(uint4*)&yb[rowb + 8] = hi4;
    *(uint4*)&yb[(size_t)4 * 2048 * 512 + rowb + 8] = lo4;
  }
}

// ---------------- output projection (128x64 m97 structure) ---------------
__global__ __launch_bounds__(256) void gemm_out(const u16* __restrict__ yhi,
                                                const u16* __restrict__ ylo,
                                                const u16* __restrict__ whi,
                                                const u16* __restrict__ wlo,
                                                const float* __restrict__ b_out,
                                                float* __restrict__ out) {
  __shared__ u16 Ah[128 * 64];
  __shared__ u16 Al[128 * 64];
  __shared__ u16 Bh[64 * 64];
  __shared__ u16 Bl[64 * 64];
  const int bid = blockIdx.x;
  const int xcd = bid & 7, rr = bid >> 3;       // rr in [0,64)
  const int m0 = (xcd * 8 + (rr & 7)) * 128;    // 64 m-tiles
  const int n0 = (rr >> 3) * 64;                // 8 n-tiles
  const int tid  = threadIdx.x;
  const int lane = tid & 63, w = tid >> 6;
  const int wm = w >> 1, wn = w & 1;
  const int quad = lane >> 4, l15 = lane & 15;
  const int sw0 = ((quad)     ^ (l15 & 7)) * 8;
  const int sw1 = ((quad + 4) ^ (l15 & 7)) * 8;

  f32x4 acc[4][2] = {};

  for (int kt = 0; kt < 8; kt++) {
    const int k0 = kt * 64;
    stage_ld512<128>(yhi + (size_t)m0 * 512 + k0, Ah, tid);
    stage_ld512<128>(ylo + (size_t)m0 * 512 + k0, Al, tid);
    stage_ld512<64>(whi + (size_t)n0 * 512 + k0, Bh, tid);
    stage_ld512<64>(wlo + (size_t)n0 * 512 + k0, Bl, tid);
    __syncthreads();
#pragma unroll
    for (int ks = 0; ks < 2; ks++) {
      const int sw = ks ? sw1 : sw0;
      bf16x8 afh[4], afl[4], bfh[2], bfl[2];
#pragma unroll
      for (int ri = 0; ri < 4; ri++) {
        afh[ri] = *(const bf16x8*)&Ah[(wm * 64 + ri * 16 + l15) * 64 + sw];
        afl[ri] = *(const bf16x8*)&Al[(wm * 64 + ri * 16 + l15) * 64 + sw];
      }
#pragma unroll
      for (int ci = 0; ci < 2; ci++) {
        bfh[ci] = *(const bf16x8*)&Bh[(wn * 32 + ci * 16 + l15) * 64 + sw];
        bfl[ci] = *(const bf16x8*)&Bl[(wn * 32 + ci * 16 + l15) * 64 + sw];
      }
#pragma unroll
      for (int ri = 0; ri < 4; ri++)
#pragma unroll
        for (int ci = 0; ci < 2; ci++) {
          acc[ri][ci] = MFMA16(afh[ri], bfh[ci], acc[ri][ci]);
          acc[ri][ci] = MFMA16(afh[ri], bfl[ci], acc[ri][ci]);
          acc[ri][ci] = MFMA16(afl[ri], bfh[ci], acc[ri][ci]);
        }
    }
    __syncthreads();
  }

#pragma unroll
  for (int ri = 0; ri < 4; ri++) {
#pragma unroll
    for (int ci = 0; ci < 2; ci++) {
      int n = n0 + wn * 32 + ci * 16 + l15;
      float bias = b_out[n];
#pragma unroll
      for (int r = 0; r < 4; r++) {
        int m = m0 + wm * 64 + ri * 16 + quad * 4 + r;
        out[(size_t)m * 512 + n] = acc[ri][ci][r] + bias;
      }
    }
  }
}

// ---------------- launch ----------------
extern "C" void kernel_launch(void* const* d_in, const int* in_sizes, int n_in,
                              void* d_out, int out_size, void* d_ws, size_t ws_size,
                              hipStream_t stream) {
  const float* x      = (const float*)d_in[0];
  const float* W_attn = (const float*)d_in[1];
  const float* b_attn = (const float*)d_in[2];
  const float* W_out  = (const float*)d_in[3];
  const float* b_out  = (const float*)d_in[4];
  float* out = (float*)d_out;

  char* ws = (char*)d_ws;
  u16* xb   = (u16*)(ws + 0);                 //  8 MB  [8192][512]
  u16* wta  = (u16*)(ws + 8388608);           //  1.5MB [1536][512]
  u16* wtoh = (u16*)(ws + 9961472);           //  0.5MB [512][512]
  u16* wtol = (u16*)(ws + 10485760);          //  0.5MB
  u16* qb   = (u16*)(ws + 11010048);          //  8 MB  [bh][t][64] (pre-scaled)
  u16* kb   = (u16*)(ws + 19398656);          //  8 MB  [bh][t][64]
  u16* vtb  = (u16*)(ws + 27787264);          //  8 MB  V' frag-packed
  u16* yhi  = (u16*)(ws + 36175872);          //  8 MB  [B,T,C] (+8 MB lo plane)

  prep_kernel<<<4352, 256, 0, stream>>>(x, xb, W_attn, wta, W_out, wtoh, wtol);
  gemm_qkv<<<768, 256, 0, stream>>>(xb, wta, b_attn, qb, kb, vtb);
  flash_attn<<<dim3(16, 64), 128, 0, stream>>>(qb, kb, vtb, yhi);
  gemm_out<<<512, 256, 0, stream>>>(yhi, yhi + (size_t)4 * 2048 * 512, wtoh, wtol, b_out, out);
}

// Round 13
// 168.223 us; speedup vs baseline: 1.8433x; 1.0405x over previous
//
#include <hip/hip_runtime.h>

typedef __attribute__((ext_vector_type(8))) short bf16x8;
typedef __attribute__((ext_vector_type(4))) float f32x4;
typedef unsigned short u16;
typedef unsigned int u32;

#define MFMA16(A, B, C) __builtin_amdgcn_mfma_f32_16x16x32_bf16((A), (B), (C), 0, 0, 0)

#if __has_builtin(__builtin_amdgcn_exp2f)
#define EXP2(x) __builtin_amdgcn_exp2f(x)
#else
#define EXP2(x) exp2f(x)
#endif

typedef __attribute__((address_space(3))) unsigned int lds_u32;
typedef const __attribute__((address_space(1))) unsigned int glb_u32;

__device__ __forceinline__ u16 f2bf(float f) {
  union { float f; unsigned u; } x; x.f = f;
  unsigned r = (x.u + 0x7fffu + ((x.u >> 16) & 1u)) >> 16;
  return (u16)r;
}
__device__ __forceinline__ float bf2f(u16 h) {
  union { float f; unsigned u; } x; x.u = ((unsigned)h) << 16;
  return x.f;
}

// 256-thread stagers -----------------------------------------------------
__device__ __forceinline__ void stage_sw64(const u16* src, u16* lds, int tid) {
#pragma unroll
  for (int i = 0; i < 2; i++) {
    int vv = tid + i * 256;
    int row = vv >> 3, c = vv & 7;
    const u16* gp = src + (size_t)row * 64 + (size_t)(c ^ (row & 7)) * 8;
    __builtin_amdgcn_global_load_lds((glb_u32*)gp,
        (lds_u32*)(lds + (size_t)(i * 256 + (tid & 192)) * 8), 16, 0, 0);
  }
}

__device__ __forceinline__ void stage_lin64(const u16* src, u16* lds, int tid) {
#pragma unroll
  for (int i = 0; i < 2; i++) {
    const u16* gp = src + (size_t)(i * 256 + tid) * 8;
    __builtin_amdgcn_global_load_lds((glb_u32*)gp,
        (lds_u32*)(lds + (size_t)(i * 256 + (tid & 192)) * 8), 16, 0, 0);
  }
}

template <int ROWS>
__device__ __forceinline__ void stage_ld512(const u16* src, u16* lds, int tid) {
#pragma unroll
  for (int i = 0; i < ROWS / 32; i++) {
    int vv = tid + i * 256;
    int row = vv >> 3, c = vv & 7;
    const u16* gp = src + (size_t)row * 512 + (size_t)(c ^ (row & 7)) * 8;
    __builtin_amdgcn_global_load_lds((glb_u32*)gp,
        (lds_u32*)(lds + (size_t)(i * 256 + (tid & 192)) * 8), 16, 0, 0);
  }
}

// ---------------- fused prep kernel ----------------
__global__ __launch_bounds__(256) void prep_kernel(const float* __restrict__ x,
                                                   u16* __restrict__ xb,
                                                   const float* __restrict__ Wa,
                                                   u16* __restrict__ wta,
                                                   const float* __restrict__ Wo,
                                                   u16* __restrict__ whi,
                                                   u16* __restrict__ wlo) {
  __shared__ u16 Th[64][72];
  __shared__ u16 Tl[64][72];
  const int bid = blockIdx.x;
  const int tid = threadIdx.x;

  if (bid < 4096) {
    int i = bid * 256 + tid;
    float4 v = ((const float4*)x)[i];
    ushort4 o;
    o.x = f2bf(v.x); o.y = f2bf(v.y); o.z = f2bf(v.z); o.w = f2bf(v.w);
    ((ushort4*)xb)[i] = o;
    return;
  }

  if (bid < 4288) {
    const int t = bid - 4096;
    const int n0 = (t % 24) * 64;
    const int k0 = (t / 24) * 64;
    const int r = tid >> 4, c4 = (tid & 15) * 4;
#pragma unroll
    for (int i = 0; i < 4; i++) {
      int row = r + i * 16;
      float4 v = *(const float4*)&Wa[(size_t)(k0 + row) * 1536 + n0 + c4];
      Th[c4 + 0][row] = f2bf(v.x);
      Th[c4 + 1][row] = f2bf(v.y);
      Th[c4 + 2][row] = f2bf(v.z);
      Th[c4 + 3][row] = f2bf(v.w);
    }
    __syncthreads();
    const int row = tid >> 2, c16 = (tid & 3) * 16;
    *(uint4*)&wta[(size_t)(n0 + row) * 512 + k0 + c16]     = *(uint4*)&Th[row][c16];
    *(uint4*)&wta[(size_t)(n0 + row) * 512 + k0 + c16 + 8] = *(uint4*)&Th[row][c16 + 8];
    return;
  }

  {
    const int t = bid - 4288;
    const int n0 = (t & 7) * 64;
    const int k0 = (t >> 3) * 64;
    const int r = tid >> 4, c4 = (tid & 15) * 4;
#pragma unroll
    for (int i = 0; i < 4; i++) {
      int row = r + i * 16;
      float4 v = *(const float4*)&Wo[(size_t)(k0 + row) * 512 + n0 + c4];
      float vv[4] = {v.x, v.y, v.z, v.w};
#pragma unroll
      for (int jj = 0; jj < 4; jj++) {
        u16 hi = f2bf(vv[jj]);
        Th[c4 + jj][row] = hi;
        Tl[c4 + jj][row] = f2bf(vv[jj] - bf2f(hi));
      }
    }
    __syncthreads();
    const int row = tid >> 2, c16 = (tid & 3) * 16;
    *(uint4*)&whi[(size_t)(n0 + row) * 512 + k0 + c16]     = *(uint4*)&Th[row][c16];
    *(uint4*)&whi[(size_t)(n0 + row) * 512 + k0 + c16 + 8] = *(uint4*)&Th[row][c16 + 8];
    *(uint4*)&wlo[(size_t)(n0 + row) * 512 + k0 + c16]     = *(uint4*)&Tl[row][c16];
    *(uint4*)&wlo[(size_t)(n0 + row) * 512 + k0 + c16 + 8] = *(uint4*)&Tl[row][c16 + 8];
  }
}

// ---------------- QKV GEMM (128x128 single-buf + coalesced epilogue) -----
__global__ __launch_bounds__(256) void gemm_qkv(const u16* __restrict__ xb,
                                                const u16* __restrict__ wta,
                                                const float* __restrict__ b_attn,
                                                u16* __restrict__ q,
                                                u16* __restrict__ kk,
                                                u16* __restrict__ v) {
  __shared__ u16 Smem[18432];  // [0,8192)=A, [8192,16384)=B, rest epilogue pad
  const int bid = blockIdx.x;
  const int xcd = bid & 7, rr = bid >> 3;       // rr in [0,96)
  const int m0 = (xcd * 8 + (rr & 7)) * 128;    // 64 m-tiles
  const int n0 = (rr >> 3) * 128;               // 12 n-tiles
  const int tid  = threadIdx.x;
  const int lane = tid & 63, w = tid >> 6;
  const int wm = w >> 1, wn = w & 1;
  const int quad = lane >> 4, l15 = lane & 15;
  const int sw0 = ((quad)     ^ (l15 & 7)) * 8;
  const int sw1 = ((quad + 4) ^ (l15 & 7)) * 8;

  f32x4 acc[4][4] = {};

  for (int kt = 0; kt < 8; kt++) {
    stage_ld512<128>(xb  + (size_t)m0 * 512 + kt * 64, Smem, tid);
    stage_ld512<128>(wta + (size_t)n0 * 512 + kt * 64, Smem + 8192, tid);
    __syncthreads();
#pragma unroll
    for (int ks = 0; ks < 2; ks++) {
      const int sw = ks ? sw1 : sw0;
      bf16x8 af[4], bf[4];
#pragma unroll
      for (int ri = 0; ri < 4; ri++)
        af[ri] = *(const bf16x8*)&Smem[(wm * 64 + ri * 16 + l15) * 64 + sw];
#pragma unroll
      for (int ci = 0; ci < 4; ci++)
        bf[ci] = *(const bf16x8*)&Smem[8192 + (wn * 64 + ci * 16 + l15) * 64 + sw];
#pragma unroll
      for (int ri = 0; ri < 4; ri++)
#pragma unroll
        for (int ci = 0; ci < 4; ci++)
          acc[ri][ci] = MFMA16(af[ri], bf[ci], acc[ri][ci]);
    }
    __syncthreads();
  }

  const float QS = 0.18033688011112043f;  // 0.125 * log2(e)
  const int wave_n0 = n0 + wn * 64;
  const int chunk = wave_n0 >> 9;
  const int h = (wave_n0 & 511) >> 6;
  const int m_wave = m0 + wm * 64;
  const int b = m_wave >> 11, t0 = m_wave & 2047;
  const int bh = b * 8 + h;

  if (chunk < 2) {
    u16* T = Smem + w * 4608;  // 64 x 72 per-wave scratch (post-barrier reuse)
    u16* dst = (chunk == 0) ? q : kk;
    const float scale = (chunk == 0) ? QS : 1.0f;
#pragma unroll
    for (int ri = 0; ri < 4; ri++)
#pragma unroll
      for (int ci = 0; ci < 4; ci++) {
        float bias = b_attn[wave_n0 + ci * 16 + l15];
#pragma unroll
        for (int r = 0; r < 4; r++) {
          int tl = ri * 16 + quad * 4 + r;
          T[tl * 72 + ci * 16 + l15] = f2bf((acc[ri][ci][r] + bias) * scale);
        }
      }
    u16* gdst = dst + (size_t)(bh * 2048 + t0 + lane) * 64;
#pragma unroll
    for (int j = 0; j < 8; j++)
      *(uint4*)&gdst[j * 8] = *(const uint4*)&T[lane * 72 + j * 8];
  } else {
#pragma unroll
    for (int ri = 0; ri < 4; ri++)
#pragma unroll
      for (int ci = 0; ci < 4; ci++) {
        int n = wave_n0 + ci * 16 + l15;
        float bias = b_attn[n];
        int d = n & 63;
        int tv = t0 + ri * 16 + quad * 4;
        int it = tv >> 7, ks2 = (tv >> 5) & 3, qd = (tv >> 3) & 3, jj = tv & 7;
        ushort4 pk;
        pk.x = f2bf(acc[ri][ci][0] + bias);
        pk.y = f2bf(acc[ri][ci][1] + bias);
        pk.z = f2bf(acc[ri][ci][2] + bias);
        pk.w = f2bf(acc[ri][ci][3] + bias);
        size_t idx = ((((size_t)bh * 16 + it) * 4 + ks2) * 64 + d) * 32 + qd * 8 + jj;
        *(ushort4*)&v[idx] = pk;
      }
  }
}

// ---------------- flash attention ----------------
// r13: r12's qh=2 K/V-amortization CONFIRMED (MfmaUtil 24->26, conflicts
// -33%, dur -8%) but 40KB x 4 = exactly 160KB LDS -> only ~2.85 blocks/CU
// resident (Occ 17.8%), eating the predicted gain. Now: 256-thread/4-wave
// blocks, still 32 q-rows/wave -> block covers 128 rows, 512 blocks = 2/CU
// GUARANTEED (48KB <= 80KB), 8 waves/CU, and K/V DMA amortized over 4
// waves (0.875 KB LDS traffic per q-row vs r12's 1.0).
__global__ __launch_bounds__(256, 2) void flash_attn(const u16* __restrict__ q,
                                                     const u16* __restrict__ k,
                                                     const u16* __restrict__ vt,
                                                     u16* __restrict__ yb) {
  __shared__ u16 Kb[2][64 * 64];      // 16 KB
  __shared__ u16 Vb[2][64 * 64];      // 16 KB
  __shared__ u16 P_lds[4 * 2 * 1024]; // 16 KB: 4 waves x 2 qh x [16q][64k] swizzled
  // total = 49152 B -> 2 blocks/CU

  const int flat = blockIdx.y * 16 + blockIdx.x;   // 512 blocks
  const int bh = (flat & 7) * 4 + ((flat >> 3) & 3);  // 4 bh per XCD band
  const int qt = flat >> 5;                        // 0..15, 128 q-rows each

  const int tid  = threadIdx.x;        // 0..255
  const int lane = tid & 63, w = tid >> 6;  // w in {0..3}
  const int quad = lane >> 4, l15 = lane & 15;
  const int sw0 = ((quad)     ^ (l15 & 7)) * 8;
  const int sw1 = ((quad + 4) ^ (l15 & 7)) * 8;

  const u16* qp = q  + (size_t)bh * 131072;
  const u16* kp = k  + (size_t)bh * 131072;
  const u16* vp = vt + (size_t)bh * 131072;

  // wave owns 32 q-rows: qt*128 + w*32 + qh*16 + l15
  bf16x8 qf[2][2];
#pragma unroll
  for (int qh = 0; qh < 2; qh++)
#pragma unroll
    for (int ks = 0; ks < 2; ks++)
      qf[qh][ks] = *(const bf16x8*)(qp + (size_t)(qt * 128 + w * 32 + qh * 16 + l15) * 64 + ks * 32 + quad * 8);

  f32x4 l_acc[2] = {};
  f32x4 o[2][4] = {};

  bf16x8 ones;
  {
    short one = (short)0x3F80;
    ones = (bf16x8){one, one, one, one, one, one, one, one};
  }

  u16* Pw = &P_lds[w * 2048];      // 2 qh x 1024 u16
  const int psw = l15 & 7;

  stage_sw64(kp, Kb[0], tid);
  stage_lin64(vp, Vb[0], tid);

  for (int it = 0; it < 32; it++) {
    __syncthreads();   // K[it],V[it] landed; prior reads of overwritten bufs done
    if (it < 31) {
      stage_sw64(kp + (size_t)(it + 1) * 4096, Kb[(it + 1) & 1], tid);
      stage_lin64(vp + (size_t)(it + 1) * 4096, Vb[(it + 1) & 1], tid);
    }
    const u16* Kc = Kb[it & 1];
    const u16* Vc = Vb[it & 1];

    // S phase: each K fragment read once, used by BOTH q-halves
#pragma unroll
    for (int jt = 0; jt < 4; jt++) {
      bf16x8 kf0 = *(const bf16x8*)&Kc[(jt * 16 + l15) * 64 + sw0];
      bf16x8 kf1 = *(const bf16x8*)&Kc[(jt * 16 + l15) * 64 + sw1];
      const int c = jt * 2 + (quad >> 1);
#pragma unroll
      for (int qh = 0; qh < 2; qh++) {
        f32x4 s = {0.f, 0.f, 0.f, 0.f};
        s = MFMA16(kf0, qf[qh][0], s);
        s = MFMA16(kf1, qf[qh][1], s);
        u32 pb[4];
#pragma unroll
        for (int r = 0; r < 4; r++) pb[r] = __float_as_uint(EXP2(s[r]));
        uint2 pk;
        pk.x = __builtin_amdgcn_perm(pb[1], pb[0], 0x07060302u);
        pk.y = __builtin_amdgcn_perm(pb[3], pb[2], 0x07060302u);
        *(uint2*)&Pw[qh * 1024 + l15 * 64 + ((c ^ psw) << 3) + (quad & 1) * 4] = pk;
      }
    }

    // PV phase: each V fragment read once, used by BOTH q-halves
    __builtin_amdgcn_s_setprio(1);
#pragma unroll
    for (int ks = 0; ks < 2; ks++) {
      bf16x8 pf0 = *(const bf16x8*)&Pw[       l15 * 64 + (((ks * 4 + quad) ^ psw) << 3)];
      bf16x8 pf1 = *(const bf16x8*)&Pw[1024 + l15 * 64 + (((ks * 4 + quad) ^ psw) << 3)];
      l_acc[0] = MFMA16(pf0, ones, l_acc[0]);
      l_acc[1] = MFMA16(pf1, ones, l_acc[1]);
#pragma unroll
      for (int dt = 0; dt < 4; dt++) {
        bf16x8 vf = *(const bf16x8*)&Vc[ks * 2048 + (dt * 16 + l15) * 32 + quad * 8];
        o[0][dt] = MFMA16(pf0, vf, o[0][dt]);
        o[1][dt] = MFMA16(pf1, vf, o[1][dt]);
      }
    }
    __builtin_amdgcn_s_setprio(0);
  }

  __syncthreads();  // all waves done with Kb/Vb; safe to reuse K region

  // epilogue per q-half: normalize, LDS transpose (K/V-region scratch), store
  const int b = bh >> 3, h = bh & 7;
  u32* Tw = (u32*)(&Kb[0][0]) + (size_t)w * 1088;  // 16 x 68 u32 per wave
#pragma unroll
  for (int qh = 0; qh < 2; qh++) {
#pragma unroll
    for (int r = 0; r < 4; r++) {
      float inv = 1.f / l_acc[qh][r];
#pragma unroll
      for (int dt = 0; dt < 4; dt++) {
        float val = o[qh][dt][r] * inv;
        u16 hi = f2bf(val);
        u16 lo = f2bf(val - bf2f(hi));
        Tw[(quad * 4 + r) * 68 + dt * 16 + l15] = (u32)hi | ((u32)lo << 16);
      }
    }
    int t = qt * 128 + w * 32 + qh * 16 + l15;
    size_t rowb = (size_t)(b * 2048 + t) * 512 + h * 64 + quad * 16;
    uint4 g0 = *(uint4*)&Tw[l15 * 68 + quad * 16 + 0];
    uint4 g1 = *(uint4*)&Tw[l15 * 68 + quad * 16 + 4];
    uint4 g2 = *(uint4*)&Tw[l15 * 68 + quad * 16 + 8];
    uint4 g3 = *(uint4*)&Tw[l15 * 68 + quad * 16 + 12];
    uint4 hi4, lo4;
    hi4.x = __builtin_amdgcn_perm(g0.y, g0.x, 0x05040100u);
    hi4.y = __builtin_amdgcn_perm(g0.w, g0.z, 0x05040100u);
    hi4.z = __builtin_amdgcn_perm(g1.y, g1.x, 0x05040100u);
    hi4.w = __builtin_amdgcn_perm(g1.w, g1.z, 0x05040100u);
    lo4.x = __builtin_amdgcn_perm(g0.y, g0.x, 0x07060302u);
    lo4.y = __builtin_amdgcn_perm(g0.w, g0.z, 0x07060302u);
    lo4.z = __builtin_amdgcn_perm(g1.y, g1.x, 0x07060302u);
    lo4.w = __builtin_amdgcn_perm(g1.w, g1.z, 0x07060302u);
    *(uint4*)&yb[rowb] = hi4;
    *(uint4*)&yb[(size_t)4 * 2048 * 512 + rowb] = lo4;
    hi4.x = __builtin_amdgcn_perm(g2.y, g2.x, 0x05040100u);
    hi4.y = __builtin_amdgcn_perm(g2.w, g2.z, 0x05040100u);
    hi4.z = __builtin_amdgcn_perm(g3.y, g3.x, 0x05040100u);
    hi4.w = __builtin_amdgcn_perm(g3.w, g3.z, 0x05040100u);
    lo4.x = __builtin_amdgcn_perm(g2.y, g2.x, 0x07060302u);
    lo4.y = __builtin_amdgcn_perm(g2.w, g2.z, 0x07060302u);
    lo4.z = __builtin_amdgcn_perm(g3.y, g3.x, 0x07060302u);
    lo4.w = __builtin_amdgcn_perm(g3.w, g3.z, 0x07060302u);
    *(uint4*)&yb[rowb + 8] = hi4;
    *(uint4*)&yb[(size_t)4 * 2048 * 512 + rowb + 8] = lo4;
  }
}

// ---------------- output projection (128x64 m97 structure) ---------------
__global__ __launch_bounds__(256) void gemm_out(const u16* __restrict__ yhi,
                                                const u16* __restrict__ ylo,
                                                const u16* __restrict__ whi,
                                                const u16* __restrict__ wlo,
                                                const float* __restrict__ b_out,
                                                float* __restrict__ out) {
  __shared__ u16 Ah[128 * 64];
  __shared__ u16 Al[128 * 64];
  __shared__ u16 Bh[64 * 64];
  __shared__ u16 Bl[64 * 64];
  const int bid = blockIdx.x;
  const int xcd = bid & 7, rr = bid >> 3;       // rr in [0,64)
  const int m0 = (xcd * 8 + (rr & 7)) * 128;    // 64 m-tiles
  const int n0 = (rr >> 3) * 64;                // 8 n-tiles
  const int tid  = threadIdx.x;
  const int lane = tid & 63, w = tid >> 6;
  const int wm = w >> 1, wn = w & 1;
  const int quad = lane >> 4, l15 = lane & 15;
  const int sw0 = ((quad)     ^ (l15 & 7)) * 8;
  const int sw1 = ((quad + 4) ^ (l15 & 7)) * 8;

  f32x4 acc[4][2] = {};

  for (int kt = 0; kt < 8; kt++) {
    const int k0 = kt * 64;
    stage_ld512<128>(yhi + (size_t)m0 * 512 + k0, Ah, tid);
    stage_ld512<128>(ylo + (size_t)m0 * 512 + k0, Al, tid);
    stage_ld512<64>(whi + (size_t)n0 * 512 + k0, Bh, tid);
    stage_ld512<64>(wlo + (size_t)n0 * 512 + k0, Bl, tid);
    __syncthreads();
#pragma unroll
    for (int ks = 0; ks < 2; ks++) {
      const int sw = ks ? sw1 : sw0;
      bf16x8 afh[4], afl[4], bfh[2], bfl[2];
#pragma unroll
      for (int ri = 0; ri < 4; ri++) {
        afh[ri] = *(const bf16x8*)&Ah[(wm * 64 + ri * 16 + l15) * 64 + sw];
        afl[ri] = *(const bf16x8*)&Al[(wm * 64 + ri * 16 + l15) * 64 + sw];
      }
#pragma unroll
      for (int ci = 0; ci < 2; ci++) {
        bfh[ci] = *(const bf16x8*)&Bh[(wn * 32 + ci * 16 + l15) * 64 + sw];
        bfl[ci] = *(const bf16x8*)&Bl[(wn * 32 + ci * 16 + l15) * 64 + sw];
      }
#pragma unroll
      for (int ri = 0; ri < 4; ri++)
#pragma unroll
        for (int ci = 0; ci < 2; ci++) {
          acc[ri][ci] = MFMA16(afh[ri], bfh[ci], acc[ri][ci]);
          acc[ri][ci] = MFMA16(afh[ri], bfl[ci], acc[ri][ci]);
          acc[ri][ci] = MFMA16(afl[ri], bfh[ci], acc[ri][ci]);
        }
    }
    __syncthreads();
  }

#pragma unroll
  for (int ri = 0; ri < 4; ri++) {
#pragma unroll
    for (int ci = 0; ci < 2; ci++) {
      int n = n0 + wn * 32 + ci * 16 + l15;
      float bias = b_out[n];
#pragma unroll
      for (int r = 0; r < 4; r++) {
        int m = m0 + wm * 64 + ri * 16 + quad * 4 + r;
        out[(size_t)m * 512 + n] = acc[ri][ci][r] + bias;
      }
    }
  }
}

// ---------------- launch ----------------
extern "C" void kernel_launch(void* const* d_in, const int* in_sizes, int n_in,
                              void* d_out, int out_size, void* d_ws, size_t ws_size,
                              hipStream_t stream) {
  const float* x      = (const float*)d_in[0];
  const float* W_attn = (const float*)d_in[1];
  const float* b_attn = (const float*)d_in[2];
  const float* W_out  = (const float*)d_in[3];
  const float* b_out  = (const float*)d_in[4];
  float* out = (float*)d_out;

  char* ws = (char*)d_ws;
  u16* xb   = (u16*)(ws + 0);                 //  8 MB  [8192][512]
  u16* wta  = (u16*)(ws + 8388608);           //  1.5MB [1536][512]
  u16* wtoh = (u16*)(ws + 9961472);           //  0.5MB [512][512]
  u16* wtol = (u16*)(ws + 10485760);          //  0.5MB
  u16* qb   = (u16*)(ws + 11010048);          //  8 MB  [bh][t][64] (pre-scaled)
  u16* kb   = (u16*)(ws + 19398656);          //  8 MB  [bh][t][64]
  u16* vtb  = (u16*)(ws + 27787264);          //  8 MB  V' frag-packed
  u16* yhi  = (u16*)(ws + 36175872);          //  8 MB  [B,T,C] (+8 MB lo plane)

  prep_kernel<<<4352, 256, 0, stream>>>(x, xb, W_attn, wta, W_out, wtoh, wtol);
  gemm_qkv<<<768, 256, 0, stream>>>(xb, wta, b_attn, qb, kb, vtb);
  flash_attn<<<dim3(16, 32), 256, 0, stream>>>(qb, kb, vtb, yhi);
  gemm_out<<<512, 256, 0, stream>>>(yhi, yhi + (size_t)4 * 2048 * 512, wtoh, wtol, b_out, out);
}

// Round 14
// 161.997 us; speedup vs baseline: 1.9142x; 1.0384x over previous
//
#include <hip/hip_runtime.h>

typedef __attribute__((ext_vector_type(8))) short bf16x8;
typedef __attribute__((ext_vector_type(4))) float f32x4;
typedef __attribute__((ext_vector_type(4))) unsigned int u32x4;
typedef unsigned short u16;
typedef unsigned int u32;

#define MFMA16(A, B, C) __builtin_amdgcn_mfma_f32_16x16x32_bf16((A), (B), (C), 0, 0, 0)

#if __has_builtin(__builtin_amdgcn_exp2f)
#define EXP2(x) __builtin_amdgcn_exp2f(x)
#else
#define EXP2(x) exp2f(x)
#endif

typedef __attribute__((address_space(3))) unsigned int lds_u32;
typedef const __attribute__((address_space(1))) unsigned int glb_u32;

__device__ __forceinline__ u16 f2bf(float f) {
  union { float f; unsigned u; } x; x.f = f;
  unsigned r = (x.u + 0x7fffu + ((x.u >> 16) & 1u)) >> 16;
  return (u16)r;
}
__device__ __forceinline__ float bf2f(u16 h) {
  union { float f; unsigned u; } x; x.u = ((unsigned)h) << 16;
  return x.f;
}

// K stager for flash: XOR-swizzled AND row-permuted. LDS row (jt*16+p)
// holds global K-row (p>>2)*8 + (jt&1)*4 + (p&3) + (jt>>1)*32, so each
// lane's S-MFMA outputs land exactly on its PV A-fragment k-slots
// (k = ks*32 + quad*8 + j) -> P stays in registers, no LDS round-trip.
// global_load_lds source addr is per-lane (guide §5), so this is free.
__device__ __forceinline__ void stage_swK(const u16* src, u16* lds, int tid) {
#pragma unroll
  for (int i = 0; i < 2; i++) {
    int vv = tid + i * 256;
    int row = vv >> 3, c = vv & 7;          // LDS row 0..63, 16B chunk
    int p = row & 15, jt = row >> 4;
    int krow = ((p >> 2) << 3) + ((jt & 1) << 2) + (p & 3) + ((jt >> 1) << 5);
    const u16* gp = src + (size_t)krow * 64 + (size_t)(c ^ (row & 7)) * 8;
    __builtin_amdgcn_global_load_lds((glb_u32*)gp,
        (lds_u32*)(lds + (size_t)(i * 256 + (tid & 192)) * 8), 16, 0, 0);
  }
}

__device__ __forceinline__ void stage_lin64(const u16* src, u16* lds, int tid) {
#pragma unroll
  for (int i = 0; i < 2; i++) {
    const u16* gp = src + (size_t)(i * 256 + tid) * 8;
    __builtin_amdgcn_global_load_lds((glb_u32*)gp,
        (lds_u32*)(lds + (size_t)(i * 256 + (tid & 192)) * 8), 16, 0, 0);
  }
}

template <int ROWS>
__device__ __forceinline__ void stage_ld512(const u16* src, u16* lds, int tid) {
#pragma unroll
  for (int i = 0; i < ROWS / 32; i++) {
    int vv = tid + i * 256;
    int row = vv >> 3, c = vv & 7;
    const u16* gp = src + (size_t)row * 512 + (size_t)(c ^ (row & 7)) * 8;
    __builtin_amdgcn_global_load_lds((glb_u32*)gp,
        (lds_u32*)(lds + (size_t)(i * 256 + (tid & 192)) * 8), 16, 0, 0);
  }
}

// ---------------- fused prep kernel ----------------
__global__ __launch_bounds__(256) void prep_kernel(const float* __restrict__ x,
                                                   u16* __restrict__ xb,
                                                   const float* __restrict__ Wa,
                                                   u16* __restrict__ wta,
                                                   const float* __restrict__ Wo,
                                                   u16* __restrict__ whi,
                                                   u16* __restrict__ wlo) {
  __shared__ u16 Th[64][72];
  __shared__ u16 Tl[64][72];
  const int bid = blockIdx.x;
  const int tid = threadIdx.x;

  if (bid < 4096) {
    int i = bid * 256 + tid;
    float4 v = ((const float4*)x)[i];
    ushort4 o;
    o.x = f2bf(v.x); o.y = f2bf(v.y); o.z = f2bf(v.z); o.w = f2bf(v.w);
    ((ushort4*)xb)[i] = o;
    return;
  }

  if (bid < 4288) {
    const int t = bid - 4096;
    const int n0 = (t % 24) * 64;
    const int k0 = (t / 24) * 64;
    const int r = tid >> 4, c4 = (tid & 15) * 4;
#pragma unroll
    for (int i = 0; i < 4; i++) {
      int row = r + i * 16;
      float4 v = *(const float4*)&Wa[(size_t)(k0 + row) * 1536 + n0 + c4];
      Th[c4 + 0][row] = f2bf(v.x);
      Th[c4 + 1][row] = f2bf(v.y);
      Th[c4 + 2][row] = f2bf(v.z);
      Th[c4 + 3][row] = f2bf(v.w);
    }
    __syncthreads();
    const int row = tid >> 2, c16 = (tid & 3) * 16;
    *(uint4*)&wta[(size_t)(n0 + row) * 512 + k0 + c16]     = *(uint4*)&Th[row][c16];
    *(uint4*)&wta[(size_t)(n0 + row) * 512 + k0 + c16 + 8] = *(uint4*)&Th[row][c16 + 8];
    return;
  }

  {
    const int t = bid - 4288;
    const int n0 = (t & 7) * 64;
    const int k0 = (t >> 3) * 64;
    const int r = tid >> 4, c4 = (tid & 15) * 4;
#pragma unroll
    for (int i = 0; i < 4; i++) {
      int row = r + i * 16;
      float4 v = *(const float4*)&Wo[(size_t)(k0 + row) * 512 + n0 + c4];
      float vv[4] = {v.x, v.y, v.z, v.w};
#pragma unroll
      for (int jj = 0; jj < 4; jj++) {
        u16 hi = f2bf(vv[jj]);
        Th[c4 + jj][row] = hi;
        Tl[c4 + jj][row] = f2bf(vv[jj] - bf2f(hi));
      }
    }
    __syncthreads();
    const int row = tid >> 2, c16 = (tid & 3) * 16;
    *(uint4*)&whi[(size_t)(n0 + row) * 512 + k0 + c16]     = *(uint4*)&Th[row][c16];
    *(uint4*)&whi[(size_t)(n0 + row) * 512 + k0 + c16 + 8] = *(uint4*)&Th[row][c16 + 8];
    *(uint4*)&wlo[(size_t)(n0 + row) * 512 + k0 + c16]     = *(uint4*)&Tl[row][c16];
    *(uint4*)&wlo[(size_t)(n0 + row) * 512 + k0 + c16 + 8] = *(uint4*)&Tl[row][c16 + 8];
  }
}

// ---------------- QKV GEMM (128x128 single-buf + coalesced epilogue) -----
__global__ __launch_bounds__(256) void gemm_qkv(const u16* __restrict__ xb,
                                                const u16* __restrict__ wta,
                                                const float* __restrict__ b_attn,
                                                u16* __restrict__ q,
                                                u16* __restrict__ kk,
                                                u16* __restrict__ v) {
  __shared__ u16 Smem[18432];  // [0,8192)=A, [8192,16384)=B, rest epilogue pad
  const int bid = blockIdx.x;
  const int xcd = bid & 7, rr = bid >> 3;       // rr in [0,96)
  const int m0 = (xcd * 8 + (rr & 7)) * 128;    // 64 m-tiles
  const int n0 = (rr >> 3) * 128;               // 12 n-tiles
  const int tid  = threadIdx.x;
  const int lane = tid & 63, w = tid >> 6;
  const int wm = w >> 1, wn = w & 1;
  const int quad = lane >> 4, l15 = lane & 15;
  const int sw0 = ((quad)     ^ (l15 & 7)) * 8;
  const int sw1 = ((quad + 4) ^ (l15 & 7)) * 8;

  f32x4 acc[4][4] = {};

  for (int kt = 0; kt < 8; kt++) {
    stage_ld512<128>(xb  + (size_t)m0 * 512 + kt * 64, Smem, tid);
    stage_ld512<128>(wta + (size_t)n0 * 512 + kt * 64, Smem + 8192, tid);
    __syncthreads();
#pragma unroll
    for (int ks = 0; ks < 2; ks++) {
      const int sw = ks ? sw1 : sw0;
      bf16x8 af[4], bf[4];
#pragma unroll
      for (int ri = 0; ri < 4; ri++)
        af[ri] = *(const bf16x8*)&Smem[(wm * 64 + ri * 16 + l15) * 64 + sw];
#pragma unroll
      for (int ci = 0; ci < 4; ci++)
        bf[ci] = *(const bf16x8*)&Smem[8192 + (wn * 64 + ci * 16 + l15) * 64 + sw];
#pragma unroll
      for (int ri = 0; ri < 4; ri++)
#pragma unroll
        for (int ci = 0; ci < 4; ci++)
          acc[ri][ci] = MFMA16(af[ri], bf[ci], acc[ri][ci]);
    }
    __syncthreads();
  }

  const float QS = 0.18033688011112043f;  // 0.125 * log2(e)
  const int wave_n0 = n0 + wn * 64;
  const int chunk = wave_n0 >> 9;
  const int h = (wave_n0 & 511) >> 6;
  const int m_wave = m0 + wm * 64;
  const int b = m_wave >> 11, t0 = m_wave & 2047;
  const int bh = b * 8 + h;

  if (chunk < 2) {
    u16* T = Smem + w * 4608;  // 64 x 72 per-wave scratch (post-barrier reuse)
    u16* dst = (chunk == 0) ? q : kk;
    const float scale = (chunk == 0) ? QS : 1.0f;
#pragma unroll
    for (int ri = 0; ri < 4; ri++)
#pragma unroll
      for (int ci = 0; ci < 4; ci++) {
        float bias = b_attn[wave_n0 + ci * 16 + l15];
#pragma unroll
        for (int r = 0; r < 4; r++) {
          int tl = ri * 16 + quad * 4 + r;
          T[tl * 72 + ci * 16 + l15] = f2bf((acc[ri][ci][r] + bias) * scale);
        }
      }
    u16* gdst = dst + (size_t)(bh * 2048 + t0 + lane) * 64;
#pragma unroll
    for (int j = 0; j < 8; j++)
      *(uint4*)&gdst[j * 8] = *(const uint4*)&T[lane * 72 + j * 8];
  } else {
#pragma unroll
    for (int ri = 0; ri < 4; ri++)
#pragma unroll
      for (int ci = 0; ci < 4; ci++) {
        int n = wave_n0 + ci * 16 + l15;
        float bias = b_attn[n];
        int d = n & 63;
        int tv = t0 + ri * 16 + quad * 4;
        int it = tv >> 7, ks2 = (tv >> 5) & 3, qd = (tv >> 3) & 3, jj = tv & 7;
        ushort4 pk;
        pk.x = f2bf(acc[ri][ci][0] + bias);
        pk.y = f2bf(acc[ri][ci][1] + bias);
        pk.z = f2bf(acc[ri][ci][2] + bias);
        pk.w = f2bf(acc[ri][ci][3] + bias);
        size_t idx = ((((size_t)bh * 16 + it) * 4 + ks2) * 64 + d) * 32 + qd * 8 + jj;
        *(ushort4*)&v[idx] = pk;
      }
  }
}

// ---------------- flash attention ----------------
// r14: in-register P. r12/r13 proved flash ~58us is invariant to occupancy
// and LDS traffic -> the floor is the S->P(ds_write->lgkmcnt->ds_read)->PV
// serial chain. The K-stager row permutation (stage_swK) makes each lane's
// S outputs land exactly on its PV A-fragment k-slots, so P packs straight
// into registers (pa[qh][ks], all compile-time indices). Deletes 32 LDS
// ops/wave/iter + the RAW serialization + 16KB LDS (now 32KB total).
__global__ __launch_bounds__(256, 2) void flash_attn(const u16* __restrict__ q,
                                                     const u16* __restrict__ k,
                                                     const u16* __restrict__ vt,
                                                     u16* __restrict__ yb) {
  __shared__ u16 Kb[2][64 * 64];      // 16 KB (row-permuted + swizzled)
  __shared__ u16 Vb[2][64 * 64];      // 16 KB
  // total = 32768 B -> 2 blocks/CU (grid-limited), 8 waves/CU

  const int flat = blockIdx.y * 16 + blockIdx.x;   // 512 blocks
  const int bh = (flat & 7) * 4 + ((flat >> 3) & 3);  // 4 bh per XCD band
  const int qt = flat >> 5;                        // 0..15, 128 q-rows each

  const int tid  = threadIdx.x;        // 0..255
  const int lane = tid & 63, w = tid >> 6;  // w in {0..3}
  const int quad = lane >> 4, l15 = lane & 15;
  const int sw0 = ((quad)     ^ (l15 & 7)) * 8;
  const int sw1 = ((quad + 4) ^ (l15 & 7)) * 8;

  const u16* qp = q  + (size_t)bh * 131072;
  const u16* kp = k  + (size_t)bh * 131072;
  const u16* vp = vt + (size_t)bh * 131072;

  // wave owns 32 q-rows: qt*128 + w*32 + qh*16 + l15
  bf16x8 qf[2][2];
#pragma unroll
  for (int qh = 0; qh < 2; qh++)
#pragma unroll
    for (int ks = 0; ks < 2; ks++)
      qf[qh][ks] = *(const bf16x8*)(qp + (size_t)(qt * 128 + w * 32 + qh * 16 + l15) * 64 + ks * 32 + quad * 8);

  f32x4 l_acc[2] = {};
  f32x4 o[2][4] = {};

  bf16x8 ones;
  {
    short one = (short)0x3F80;
    ones = (bf16x8){one, one, one, one, one, one, one, one};
  }

  stage_swK(kp, Kb[0], tid);
  stage_lin64(vp, Vb[0], tid);

  for (int it = 0; it < 32; it++) {
    __syncthreads();   // K[it],V[it] landed; prior reads of overwritten bufs done
    if (it < 31) {
      stage_swK(kp + (size_t)(it + 1) * 4096, Kb[(it + 1) & 1], tid);
      stage_lin64(vp + (size_t)(it + 1) * 4096, Vb[(it + 1) & 1], tid);
    }
    const u16* Kc = Kb[it & 1];
    const u16* Vc = Vb[it & 1];

    // S phase: K rows pre-permuted -> lane's outputs ARE its PV fragment.
    // pa[qh][ks] = P[q=l15][k = ks*32 + quad*8 + (0..7)] as 4x u32 bf16-pairs.
    u32x4 pa[2][2];
#pragma unroll
    for (int jt = 0; jt < 4; jt++) {
      bf16x8 kf0 = *(const bf16x8*)&Kc[(jt * 16 + l15) * 64 + sw0];
      bf16x8 kf1 = *(const bf16x8*)&Kc[(jt * 16 + l15) * 64 + sw1];
#pragma unroll
      for (int qh = 0; qh < 2; qh++) {
        f32x4 s = {0.f, 0.f, 0.f, 0.f};
        s = MFMA16(kf0, qf[qh][0], s);
        s = MFMA16(kf1, qf[qh][1], s);
        u32 pb[4];
#pragma unroll
        for (int r = 0; r < 4; r++) pb[r] = __float_as_uint(EXP2(s[r]));
        pa[qh][jt >> 1][(jt & 1) * 2 + 0] = __builtin_amdgcn_perm(pb[1], pb[0], 0x07060302u);
        pa[qh][jt >> 1][(jt & 1) * 2 + 1] = __builtin_amdgcn_perm(pb[3], pb[2], 0x07060302u);
      }
    }

    // PV phase: P from registers, V from LDS
    __builtin_amdgcn_s_setprio(1);
#pragma unroll
    for (int ks = 0; ks < 2; ks++) {
      bf16x8 pf0 = __builtin_bit_cast(bf16x8, pa[0][ks]);
      bf16x8 pf1 = __builtin_bit_cast(bf16x8, pa[1][ks]);
      l_acc[0] = MFMA16(pf0, ones, l_acc[0]);
      l_acc[1] = MFMA16(pf1, ones, l_acc[1]);
#pragma unroll
      for (int dt = 0; dt < 4; dt++) {
        bf16x8 vf = *(const bf16x8*)&Vc[ks * 2048 + (dt * 16 + l15) * 32 + quad * 8];
        o[0][dt] = MFMA16(pf0, vf, o[0][dt]);
        o[1][dt] = MFMA16(pf1, vf, o[1][dt]);
      }
    }
    __builtin_amdgcn_s_setprio(0);
  }

  __syncthreads();  // all waves done with Kb/Vb; safe to reuse K region

  // epilogue per q-half: normalize, LDS transpose (K/V-region scratch), store
  const int b = bh >> 3, h = bh & 7;
  u32* Tw = (u32*)(&Kb[0][0]) + (size_t)w * 1088;  // 16 x 68 u32 per wave
#pragma unroll
  for (int qh = 0; qh < 2; qh++) {
#pragma unroll
    for (int r = 0; r < 4; r++) {
      float inv = 1.f / l_acc[qh][r];
#pragma unroll
      for (int dt = 0; dt < 4; dt++) {
        float val = o[qh][dt][r] * inv;
        u16 hi = f2bf(val);
        u16 lo = f2bf(val - bf2f(hi));
        Tw[(quad * 4 + r) * 68 + dt * 16 + l15] = (u32)hi | ((u32)lo << 16);
      }
    }
    int t = qt * 128 + w * 32 + qh * 16 + l15;
    size_t rowb = (size_t)(b * 2048 + t) * 512 + h * 64 + quad * 16;
    uint4 g0 = *(uint4*)&Tw[l15 * 68 + quad * 16 + 0];
    uint4 g1 = *(uint4*)&Tw[l15 * 68 + quad * 16 + 4];
    uint4 g2 = *(uint4*)&Tw[l15 * 68 + quad * 16 + 8];
    uint4 g3 = *(uint4*)&Tw[l15 * 68 + quad * 16 + 12];
    uint4 hi4, lo4;
    hi4.x = __builtin_amdgcn_perm(g0.y, g0.x, 0x05040100u);
    hi4.y = __builtin_amdgcn_perm(g0.w, g0.z, 0x05040100u);
    hi4.z = __builtin_amdgcn_perm(g1.y, g1.x, 0x05040100u);
    hi4.w = __builtin_amdgcn_perm(g1.w, g1.z, 0x05040100u);
    lo4.x = __builtin_amdgcn_perm(g0.y, g0.x, 0x07060302u);
    lo4.y = __builtin_amdgcn_perm(g0.w, g0.z, 0x07060302u);
    lo4.z = __builtin_amdgcn_perm(g1.y, g1.x, 0x07060302u);
    lo4.w = __builtin_amdgcn_perm(g1.w, g1.z, 0x07060302u);
    *(uint4*)&yb[rowb] = hi4;
    *(uint4*)&yb[(size_t)4 * 2048 * 512 + rowb] = lo4;
    hi4.x = __builtin_amdgcn_perm(g2.y, g2.x, 0x05040100u);
    hi4.y = __builtin_amdgcn_perm(g2.w, g2.z, 0x05040100u);
    hi4.z = __builtin_amdgcn_perm(g3.y, g3.x, 0x05040100u);
    hi4.w = __builtin_amdgcn_perm(g3.w, g3.z, 0x05040100u);
    lo4.x = __builtin_amdgcn_perm(g2.y, g2.x, 0x07060302u);
    lo4.y = __builtin_amdgcn_perm(g2.w, g2.z, 0x07060302u);
    lo4.z = __builtin_amdgcn_perm(g3.y, g3.x, 0x07060302u);
    lo4.w = __builtin_amdgcn_perm(g3.w, g3.z, 0x07060302u);
    *(uint4*)&yb[rowb + 8] = hi4;
    *(uint4*)&yb[(size_t)4 * 2048 * 512 + rowb + 8] = lo4;
  }
}

// ---------------- output projection (128x64 m97 structure) ---------------
__global__ __launch_bounds__(256) void gemm_out(const u16* __restrict__ yhi,
                                                const u16* __restrict__ ylo,
                                                const u16* __restrict__ whi,
                                                const u16* __restrict__ wlo,
                                                const float* __restrict__ b_out,
                                                float* __restrict__ out) {
  __shared__ u16 Ah[128 * 64];
  __shared__ u16 Al[128 * 64];
  __shared__ u16 Bh[64 * 64];
  __shared__ u16 Bl[64 * 64];
  const int bid = blockIdx.x;
  const int xcd = bid & 7, rr = bid >> 3;       // rr in [0,64)
  const int m0 = (xcd * 8 + (rr & 7)) * 128;    // 64 m-tiles
  const int n0 = (rr >> 3) * 64;                // 8 n-tiles
  const int tid  = threadIdx.x;
  const int lane = tid & 63, w = tid >> 6;
  const int wm = w >> 1, wn = w & 1;
  const int quad = lane >> 4, l15 = lane & 15;
  const int sw0 = ((quad)     ^ (l15 & 7)) * 8;
  const int sw1 = ((quad + 4) ^ (l15 & 7)) * 8;

  f32x4 acc[4][2] = {};

  for (int kt = 0; kt < 8; kt++) {
    const int k0 = kt * 64;
    stage_ld512<128>(yhi + (size_t)m0 * 512 + k0, Ah, tid);
    stage_ld512<128>(ylo + (size_t)m0 * 512 + k0, Al, tid);
    stage_ld512<64>(whi + (size_t)n0 * 512 + k0, Bh, tid);
    stage_ld512<64>(wlo + (size_t)n0 * 512 + k0, Bl, tid);
    __syncthreads();
#pragma unroll
    for (int ks = 0; ks < 2; ks++) {
      const int sw = ks ? sw1 : sw0;
      bf16x8 afh[4], afl[4], bfh[2], bfl[2];
#pragma unroll
      for (int ri = 0; ri < 4; ri++) {
        afh[ri] = *(const bf16x8*)&Ah[(wm * 64 + ri * 16 + l15) * 64 + sw];
        afl[ri] = *(const bf16x8*)&Al[(wm * 64 + ri * 16 + l15) * 64 + sw];
      }
#pragma unroll
      for (int ci = 0; ci < 2; ci++) {
        bfh[ci] = *(const bf16x8*)&Bh[(wn * 32 + ci * 16 + l15) * 64 + sw];
        bfl[ci] = *(const bf16x8*)&Bl[(wn * 32 + ci * 16 + l15) * 64 + sw];
      }
#pragma unroll
      for (int ri = 0; ri < 4; ri++)
#pragma unroll
        for (int ci = 0; ci < 2; ci++) {
          acc[ri][ci] = MFMA16(afh[ri], bfh[ci], acc[ri][ci]);
          acc[ri][ci] = MFMA16(afh[ri], bfl[ci], acc[ri][ci]);
          acc[ri][ci] = MFMA16(afl[ri], bfh[ci], acc[ri][ci]);
        }
    }
    __syncthreads();
  }

#pragma unroll
  for (int ri = 0; ri < 4; ri++) {
#pragma unroll
    for (int ci = 0; ci < 2; ci++) {
      int n = n0 + wn * 32 + ci * 16 + l15;
      float bias = b_out[n];
#pragma unroll
      for (int r = 0; r < 4; r++) {
        int m = m0 + wm * 64 + ri * 16 + quad * 4 + r;
        out[(size_t)m * 512 + n] = acc[ri][ci][r] + bias;
      }
    }
  }
}

// ---------------- launch ----------------
extern "C" void kernel_launch(void* const* d_in, const int* in_sizes, int n_in,
                              void* d_out, int out_size, void* d_ws, size_t ws_size,
                              hipStream_t stream) {
  const float* x      = (const float*)d_in[0];
  const float* W_attn = (const float*)d_in[1];
  const float* b_attn = (const float*)d_in[2];
  const float* W_out  = (const float*)d_in[3];
  const float* b_out  = (const float*)d_in[4];
  float* out = (float*)d_out;

  char* ws = (char*)d_ws;
  u16* xb   = (u16*)(ws + 0);                 //  8 MB  [8192][512]
  u16* wta  = (u16*)(ws + 8388608);           //  1.5MB [1536][512]
  u16* wtoh = (u16*)(ws + 9961472);           //  0.5MB [512][512]
  u16* wtol = (u16*)(ws + 10485760);          //  0.5MB
  u16* qb   = (u16*)(ws + 11010048);          //  8 MB  [bh][t][64] (pre-scaled)
  u16* kb   = (u16*)(ws + 19398656);          //  8 MB  [bh][t][64]
  u16* vtb  = (u16*)(ws + 27787264);          //  8 MB  V' frag-packed
  u16* yhi  = (u16*)(ws + 36175872);          //  8 MB  [B,T,C] (+8 MB lo plane)

  prep_kernel<<<4352, 256, 0, stream>>>(x, xb, W_attn, wta, W_out, wtoh, wtol);
  gemm_qkv<<<768, 256, 0, stream>>>(xb, wta, b_attn, qb, kb, vtb);
  flash_attn<<<dim3(16, 32), 256, 0, stream>>>(qb, kb, vtb, yhi);
  gemm_out<<<512, 256, 0, stream>>>(yhi, yhi + (size_t)4 * 2048 * 512, wtoh, wtol, b_out, out);
}